// Round 1
// baseline (1345.059 us; speedup 1.0000x reference)
//
#include <hip/hip_runtime.h>
#include <hip/hip_bf16.h>
#include <math.h>

#define N_  128
#define C_  64
#define T_  128
#define V_  25
#define S_  3
#define R_  8
#define O_  64
#define BC_ 16
#define TV_ 3200   // T*V

// ---------------- K1: xm[n][c][v] = mean over t of x[n][c][t][v] ----------------
__global__ __launch_bounds__(256) void k_xm(const float* __restrict__ x,
                                            float* __restrict__ xm) {
  int nc = blockIdx.x;                       // n*64 + c
  const float* xp = x + (size_t)nc * TV_;
  __shared__ float part[250];
  int tid = threadIdx.x;
  if (tid < 250) {
    float s = 0.f;
    for (int k = 0; k < 13; ++k) {
      int idx = tid + 250 * k;               // flat t*25+v, coalesced
      if (idx < TV_) s += xp[idx];
    }
    part[tid] = s;
  }
  __syncthreads();
  if (tid < 25) {
    float s = 0.f;
    #pragma unroll
    for (int g = 0; g < 10; ++g) s += part[g * 25 + tid];
    xm[(size_t)nc * V_ + tid] = s * (1.0f / 128.0f);
  }
}

// ---------------- K2: softmaxed affinity aff[n][s][o][u][v] ----------------
__global__ __launch_bounds__(256) void k_aff(
    const float* __restrict__ xm, const float* __restrict__ PA,
    const float* __restrict__ alpha,
    const float* __restrict__ c1w, const float* __restrict__ c1b,
    const float* __restrict__ c2w, const float* __restrict__ c2b,
    const float* __restrict__ c4w, const float* __restrict__ c4b,
    float* __restrict__ aff) {
  int n = blockIdx.x, s = blockIdx.y;
  int tid = threadIdx.x;
  __shared__ float xml[1600];
  __shared__ float w1[512], w2[512], w4[512];
  __shared__ float x1l[200], x2l[200];
  __shared__ float dift[625 * 9];            // [u*25+v][r] padded 8->9 (bank-conflict-free)
  __shared__ float asym[625];
  for (int i = tid; i < 1600; i += 256) xml[i] = xm[(size_t)n * 1600 + i];
  for (int i = tid; i < 512; i += 256) {
    w1[i] = c1w[s * 512 + i];
    w2[i] = c2w[s * 512 + i];
    w4[i] = c4w[s * 512 + i];
  }
  for (int i = tid; i < 625; i += 256) {
    int u = i / 25, v = i % 25;
    asym[i] = PA[s * 625 + u * 25 + v] + PA[s * 625 + v * 25 + u];
  }
  __syncthreads();
  if (tid < 200) {
    int r = tid / 25, v = tid % 25;
    float a1 = c1b[s * R_ + r], a2 = c2b[s * R_ + r];
    #pragma unroll
    for (int c = 0; c < 64; ++c) {
      float xv = xml[c * 25 + v];
      a1 = fmaf(w1[r * 64 + c], xv, a1);
      a2 = fmaf(w2[r * 64 + c], xv, a2);
    }
    x1l[tid] = a1; x2l[tid] = a2;
  }
  __syncthreads();
  for (int i = tid; i < 5000; i += 256) {
    int r = i / 625, rem = i % 625, u = rem / 25, v = rem % 25;
    dift[(u * 25 + v) * 9 + r] = tanhf(x1l[r * 25 + u] - x2l[r * 25 + v]);
  }
  __syncthreads();
  float al = alpha[s];
  float* affp = aff + ((size_t)n * S_ + s) * (O_ * 625);
  // 800 (o,v) column-pairs: each thread does columns for o and o+32 (shares dift reads)
  for (int cp = tid; cp < 800; cp += 256) {
    int o = cp / 25, v = cp % 25;          // o in 0..31
    float avA[25], avB[25];
    float bA = c4b[s * O_ + o], bB = c4b[s * O_ + o + 32];
    #pragma unroll
    for (int u = 0; u < 25; ++u) { avA[u] = bA; avB[u] = bB; }
    #pragma unroll
    for (int u = 0; u < 25; ++u) {
      const float* dp = &dift[(u * 25 + v) * 9];
      #pragma unroll
      for (int r = 0; r < 8; ++r) {
        float d = dp[r];
        avA[u] = fmaf(w4[o * 8 + r], d, avA[u]);
        avB[u] = fmaf(w4[(o + 32) * 8 + r], d, avB[u]);
      }
    }
    float mA = -1e30f, mB = -1e30f;
    #pragma unroll
    for (int u = 0; u < 25; ++u) {
      float as_ = asym[u * 25 + v];
      avA[u] = fmaf(avA[u], al, as_);
      avB[u] = fmaf(avB[u], al, as_);
      mA = fmaxf(mA, avA[u]); mB = fmaxf(mB, avB[u]);
    }
    float sA = 0.f, sB = 0.f;
    #pragma unroll
    for (int u = 0; u < 25; ++u) {
      avA[u] = expf(avA[u] - mA); sA += avA[u];
      avB[u] = expf(avB[u] - mB); sB += avB[u];
    }
    float iA = 1.0f / sA, iB = 1.0f / sB;
    #pragma unroll
    for (int u = 0; u < 25; ++u) {
      affp[o * 625 + u * 25 + v]        = avA[u] * iA;
      affp[(o + 32) * 625 + u * 25 + v] = avB[u] * iB;
    }
  }
}

// ---------------- K3: GCN aggregate + BN + pooled partials ----------------
// block = (t-tile of 8, o-chunk of 16, n); 256 threads.
// stage1: x kept in 64 VGPRs/thread (pos = tid<200), weights via scalar loads.
// stage2: 4t x 4u register tile per thread, 2x float4 LDS reads per v.
__global__ __launch_bounds__(256) void k_gcn(
    const float* __restrict__ x, const float* __restrict__ aff,
    const float* __restrict__ c3w, const float* __restrict__ c3b,
    const float* __restrict__ gbn_g, const float* __restrict__ gbn_b,
    float* __restrict__ ybn, float* __restrict__ pooledp) {
  int tt = blockIdx.x;   // 16 tiles of 8 t
  int oc = blockIdx.y;   // 4 chunks of 16 o
  int n  = blockIdx.z;
  int t0 = tt * 8;
  int tid = threadIdx.x;
  __shared__ __align__(16) float x3s[16 * 300];   // [o][v][t pad 12]
  __shared__ __align__(16) float affs[16 * 700];  // [o][v][u pad 28]
  // zero the u-pad (u = 25..27) once; stays zero (staging only writes u<25)
  for (int i = tid; i < 16 * 25 * 3; i += 256) {
    int o = i / 75, rem = i % 75, v = rem / 3, j = rem % 3;
    affs[o * 700 + v * 28 + 25 + j] = 0.f;
  }
  float xr[64];
  const float* xb = x + (size_t)n * C_ * TV_ + t0 * 25;
  if (tid < 200) {
    #pragma unroll
    for (int c = 0; c < 64; ++c) xr[c] = xb[(size_t)c * TV_ + tid];
  }
  float acc[4][4];
  #pragma unroll
  for (int i = 0; i < 4; ++i)
    #pragma unroll
    for (int j = 0; j < 4; ++j) acc[i][j] = 0.f;
  int o_s2 = tid / 14;          // 0..15 (valid for tid<224)
  int g2   = tid % 14;
  int tg   = g2 / 7;            // 0..1  (4-t group)
  int ug   = g2 % 7;            // 0..6  (4-u group, u padded to 28)
  for (int s = 0; s < S_; ++s) {
    __syncthreads();  // prev stage2 reads (or pad-zero) done before restaging
    // stage affinity -> LDS, transposed [o][v][u]
    const float* ap = aff + (((size_t)n * S_ + s) * O_ + oc * 16) * 625;
    for (int i = tid; i < 16 * 625; i += 256) {
      int o = i / 625, rem = i % 625, u = rem / 25, v = rem % 25;
      affs[o * 700 + v * 28 + u] = ap[i];
    }
    // stage1: x3[o][t][v] for this (s, o-chunk) -> LDS transposed [o][v][t]
    if (tid < 200) {
      int tl = tid / 25, v = tid % 25;
      const float* wp = c3w + ((size_t)s * O_ + oc * 16) * 64;
      const float* bp = c3b + s * O_ + oc * 16;
      #pragma unroll
      for (int o = 0; o < 16; ++o) {
        float d0 = 0.f, d1 = 0.f, d2 = 0.f, d3 = 0.f;
        const float* w = wp + o * 64;       // block-uniform -> s_load
        #pragma unroll
        for (int c = 0; c < 64; c += 4) {
          d0 = fmaf(w[c + 0], xr[c + 0], d0);
          d1 = fmaf(w[c + 1], xr[c + 1], d1);
          d2 = fmaf(w[c + 2], xr[c + 2], d2);
          d3 = fmaf(w[c + 3], xr[c + 3], d3);
        }
        x3s[o * 300 + v * 12 + tl] = (d0 + d1) + (d2 + d3) + bp[o];
      }
    }
    __syncthreads();
    // stage2: acc[i][j] += aff[u0+j][v] * x3[t0+i][v]
    if (tid < 224) {
      const float4* x3p = reinterpret_cast<const float4*>(&x3s[o_s2 * 300 + tg * 4]);
      const float4* afp = reinterpret_cast<const float4*>(&affs[o_s2 * 700 + ug * 4]);
      #pragma unroll
      for (int v = 0; v < 25; ++v) {
        float4 xv = x3p[v * 3];
        float4 av = afp[v * 7];
        acc[0][0] = fmaf(av.x, xv.x, acc[0][0]);
        acc[0][1] = fmaf(av.y, xv.x, acc[0][1]);
        acc[0][2] = fmaf(av.z, xv.x, acc[0][2]);
        acc[0][3] = fmaf(av.w, xv.x, acc[0][3]);
        acc[1][0] = fmaf(av.x, xv.y, acc[1][0]);
        acc[1][1] = fmaf(av.y, xv.y, acc[1][1]);
        acc[1][2] = fmaf(av.z, xv.y, acc[1][2]);
        acc[1][3] = fmaf(av.w, xv.y, acc[1][3]);
        acc[2][0] = fmaf(av.x, xv.z, acc[2][0]);
        acc[2][1] = fmaf(av.y, xv.z, acc[2][1]);
        acc[2][2] = fmaf(av.z, xv.z, acc[2][2]);
        acc[2][3] = fmaf(av.w, xv.z, acc[2][3]);
        acc[3][0] = fmaf(av.x, xv.w, acc[3][0]);
        acc[3][1] = fmaf(av.y, xv.w, acc[3][1]);
        acc[3][2] = fmaf(av.z, xv.w, acc[3][2]);
        acc[3][3] = fmaf(av.w, xv.w, acc[3][3]);
      }
    }
  }
  __syncthreads();
  // BN + write + per-(n,o,tt) pooled partial (reuse x3s as reduction buffer)
  float rs = 1.0f / sqrtf(1.0f + 1e-5f);
  if (tid < 224) {
    int o = oc * 16 + o_s2;
    float sc = gbn_g[o] * rs, bb = gbn_b[o];
    float lsum = 0.f;
    float* yb = ybn + ((size_t)n * O_ + o) * TV_;
    #pragma unroll
    for (int i = 0; i < 4; ++i) {
      int t = t0 + tg * 4 + i;
      #pragma unroll
      for (int j = 0; j < 4; ++j) {
        int u = ug * 4 + j;
        if (u < 25) {
          float val = fmaf(acc[i][j], sc, bb);
          yb[t * 25 + u] = val;
          lsum += val;
        }
      }
    }
    x3s[o_s2 * 14 + tg * 7 + ug] = lsum;
  }
  __syncthreads();
  if (tid < 16) {
    float s = 0.f;
    #pragma unroll
    for (int k = 0; k < 14; ++k) s += x3s[tid * 14 + k];
    pooledp[((size_t)n * O_ + oc * 16 + tid) * 16 + tt] = s;
  }
}

// ---------------- K4: squeeze-excite gate se[n][o] ----------------
__global__ __launch_bounds__(64) void k_se(
    const float* __restrict__ pooledp,
    const float* __restrict__ att1_w, const float* __restrict__ att1_b,
    const float* __restrict__ att2_w, const float* __restrict__ att2_b,
    float* __restrict__ se) {
  int n = blockIdx.x; int tid = threadIdx.x;
  __shared__ float pooled[64]; __shared__ float hbuf[16];
  const float* pp = pooledp + ((size_t)n * 64 + tid) * 16;
  float ssum = 0.f;
  #pragma unroll
  for (int i = 0; i < 16; ++i) ssum += pp[i];
  pooled[tid] = ssum * (1.0f / 3200.0f);
  __syncthreads();
  if (tid < 16) {
    float a = att1_b[tid];
    #pragma unroll
    for (int o = 0; o < 64; ++o) a = fmaf(att1_w[tid * 64 + o], pooled[o], a);
    hbuf[tid] = fmaxf(a, 0.f);
  }
  __syncthreads();
  float a2 = att2_b[tid];
  #pragma unroll
  for (int k = 0; k < 16; ++k) a2 = fmaf(att2_w[tid * 16 + k], hbuf[k], a2);
  se[(size_t)n * 64 + tid] = 1.0f / (1.0f + expf(-a2));
}

// ---------------- K5: y2 = relu(ybn*se + x); 4x 1x1 convs; branch-3 epilogue ----
__global__ __launch_bounds__(256) void k_pw(
    const float* __restrict__ ybn, const float* __restrict__ se,
    const float* __restrict__ x,
    const float* __restrict__ br_pw, const float* __restrict__ br_pb,
    const float* __restrict__ br_pg, const float* __restrict__ br_pbeta,
    const float* __restrict__ mp_pw, const float* __restrict__ mp_pb,
    const float* __restrict__ mp_g1, const float* __restrict__ mp_b1,
    const float* __restrict__ p3w, const float* __restrict__ p3b,
    const float* __restrict__ p3g, const float* __restrict__ p3beta,
    float* __restrict__ pbuf, float* __restrict__ outp) {
  int tt = blockIdx.x; int n = blockIdx.y;
  int t0 = tt * 10;
  int npos = min(10, T_ - t0) * 25;
  int tid = threadIdx.x;
  if (tid >= npos) return;
  float rs = 1.0f / sqrtf(1.0f + 1e-5f);
  size_t base = (size_t)n * C_ * TV_ + (size_t)t0 * 25 + tid;
  const float* sep = se + (size_t)n * 64;
  float y2[64]; float xhi[16];
  #pragma unroll
  for (int o = 0; o < 64; ++o) {
    float xv = x[base + (size_t)o * TV_];
    float yv = ybn[base + (size_t)o * TV_];
    y2[o] = fmaxf(fmaf(yv, sep[o], xv), 0.f);
    if (o >= 48) xhi[o - 48] = xv;
  }
  #pragma unroll
  for (int h = 0; h < 3; ++h) {
    const float* wp = (h == 0) ? br_pw : (h == 1) ? (br_pw + 1024) : mp_pw;
    float* po = pbuf + (((size_t)h * N_ + n) * 16) * TV_ + (size_t)t0 * 25 + tid;
    #pragma unroll
    for (int bc = 0; bc < 16; ++bc) {
      float g, beta, pb;
      if (h < 2) { g = br_pg[h * 16 + bc]; beta = br_pbeta[h * 16 + bc]; pb = br_pb[h * 16 + bc]; }
      else       { g = mp_g1[bc];          beta = mp_b1[bc];             pb = mp_pb[bc]; }
      float a = 0.f;
      #pragma unroll
      for (int o = 0; o < 64; ++o) a = fmaf(wp[bc * 64 + o], y2[o], a);
      po[(size_t)bc * TV_] = fmaxf(fmaf(a + pb, g * rs, beta), 0.f);
    }
  }
  #pragma unroll
  for (int bc = 0; bc < 16; ++bc) {
    float a = 0.f;
    #pragma unroll
    for (int o = 0; o < 64; ++o) a = fmaf(p3w[bc * 64 + o], y2[o], a);
    float ov = fmaf(a + p3b[bc], p3g[bc] * rs, p3beta[bc]);   // no relu (branch 3)
    outp[base + (size_t)(48 + bc) * TV_] = fmaxf(ov + xhi[bc], 0.f);
  }
}

// ---------------- K6: temporal convs + maxpool + BN + residual + relu ----------
__global__ __launch_bounds__(256) void k_tc(
    const float* __restrict__ pbuf, const float* __restrict__ x,
    const float* __restrict__ br_tw, const float* __restrict__ br_tb,
    const float* __restrict__ br_tg, const float* __restrict__ br_tbeta,
    const float* __restrict__ mp_g2, const float* __restrict__ mp_b2,
    float* __restrict__ outp) {
  int tt = blockIdx.x; int n = blockIdx.y;
  int t0 = tt * 10;
  int npos = min(10, T_ - t0) * 25;
  int tid = threadIdx.x;
  if (tid >= npos) return;
  int tl = tid / 25, v = tid % 25;
  int t = t0 + tl;
  float rs = 1.0f / sqrtf(1.0f + 1e-5f);
  size_t xbase = (size_t)n * C_ * TV_ + (size_t)t * 25 + v;
  #pragma unroll
  for (int h = 0; h < 2; ++h) {
    int d = 1 + h;
    const float* pp = pbuf + (((size_t)h * N_ + n) * 16) * TV_ + v;
    float acc[16];
    #pragma unroll
    for (int bc = 0; bc < 16; ++bc) acc[bc] = 0.f;
    #pragma unroll
    for (int ic = 0; ic < 16; ++ic) {
      float tap[5];
      #pragma unroll
      for (int k = 0; k < 5; ++k) {
        int ts = t + (k - 2) * d;
        tap[k] = (ts >= 0 && ts < T_) ? pp[(size_t)ic * TV_ + ts * 25] : 0.f;
      }
      #pragma unroll
      for (int bc = 0; bc < 16; ++bc) {
        #pragma unroll
        for (int k = 0; k < 5; ++k)
          acc[bc] = fmaf(br_tw[((h * 16 + bc) * 16 + ic) * 5 + k], tap[k], acc[bc]);
      }
    }
    #pragma unroll
    for (int bc = 0; bc < 16; ++bc) {
      float sc  = br_tg[h * 16 + bc] * rs;
      float val = fmaf(acc[bc] + br_tb[h * 16 + bc], sc, br_tbeta[h * 16 + bc]);
      int ch = h * 16 + bc;
      float xv = x[xbase + (size_t)ch * TV_];
      outp[xbase + (size_t)ch * TV_] = fmaxf(val + xv, 0.f);
    }
  }
  {
    const float* pp = pbuf + (((size_t)2 * N_ + n) * 16) * TV_ + v;
    #pragma unroll
    for (int ic = 0; ic < 16; ++ic) {
      float m = pp[(size_t)ic * TV_ + t * 25];
      if (t > 0)      m = fmaxf(m, pp[(size_t)ic * TV_ + (t - 1) * 25]);
      if (t < T_ - 1) m = fmaxf(m, pp[(size_t)ic * TV_ + (t + 1) * 25]);
      float val = fmaf(m, mp_g2[ic] * rs, mp_b2[ic]);
      int ch = 32 + ic;
      float xv = x[xbase + (size_t)ch * TV_];
      outp[xbase + (size_t)ch * TV_] = fmaxf(val + xv, 0.f);
    }
  }
}

extern "C" void kernel_launch(void* const* d_in, const int* in_sizes, int n_in,
                              void* d_out, int out_size, void* d_ws, size_t ws_size,
                              hipStream_t stream) {
  (void)in_sizes; (void)n_in; (void)out_size; (void)ws_size;
  const float* x      = (const float*)d_in[0];
  const float* PA     = (const float*)d_in[1];
  const float* alpha  = (const float*)d_in[2];
  const float* c1w    = (const float*)d_in[3];
  const float* c1b    = (const float*)d_in[4];
  const float* c2w    = (const float*)d_in[5];
  const float* c2b    = (const float*)d_in[6];
  const float* c3w    = (const float*)d_in[7];
  const float* c3b    = (const float*)d_in[8];
  const float* c4w    = (const float*)d_in[9];
  const float* c4b    = (const float*)d_in[10];
  const float* gbn_g  = (const float*)d_in[11];
  const float* gbn_b  = (const float*)d_in[12];
  const float* att1_w = (const float*)d_in[13];
  const float* att1_b = (const float*)d_in[14];
  const float* att2_w = (const float*)d_in[15];
  const float* att2_b = (const float*)d_in[16];
  const float* br_pw  = (const float*)d_in[17];
  const float* br_pb  = (const float*)d_in[18];
  const float* br_pg  = (const float*)d_in[19];
  const float* br_pbeta = (const float*)d_in[20];
  const float* br_tw  = (const float*)d_in[21];
  const float* br_tb  = (const float*)d_in[22];
  const float* br_tg  = (const float*)d_in[23];
  const float* br_tbeta = (const float*)d_in[24];
  const float* mp_pw  = (const float*)d_in[25];
  const float* mp_pb  = (const float*)d_in[26];
  const float* mp_g1  = (const float*)d_in[27];
  const float* mp_b1  = (const float*)d_in[28];
  const float* mp_g2  = (const float*)d_in[29];
  const float* mp_b2  = (const float*)d_in[30];
  const float* p3w    = (const float*)d_in[31];
  const float* p3b    = (const float*)d_in[32];
  const float* p3g    = (const float*)d_in[33];
  const float* p3beta = (const float*)d_in[34];
  float* out = (float*)d_out;
  float* ws  = (float*)d_ws;

  // workspace layout (floats); p-buffer overlays dead aff/xm/pooled regions.
  float* se_b  = ws;                          //     8,192
  float* ybn   = ws + 8192;                   // 26,214,400
  float* aff_b = ws + 8192 + 26214400;        // 15,360,000
  float* xm_b  = aff_b + 15360000;            //    204,800
  float* pp_b  = xm_b + 204800;               //    131,072
  float* p_b   = aff_b;                       // 19,660,800 (reuse; total 183.5 MB)

  k_xm <<<dim3(N_ * C_),    dim3(256), 0, stream>>>(x, xm_b);
  k_aff<<<dim3(N_, S_),     dim3(256), 0, stream>>>(xm_b, PA, alpha, c1w, c1b, c2w, c2b,
                                                    c4w, c4b, aff_b);
  k_gcn<<<dim3(16, 4, N_),  dim3(256), 0, stream>>>(x, aff_b, c3w, c3b, gbn_g, gbn_b,
                                                    ybn, pp_b);
  k_se <<<dim3(N_),         dim3(64),  0, stream>>>(pp_b, att1_w, att1_b, att2_w, att2_b, se_b);
  k_pw <<<dim3(13, N_),     dim3(256), 0, stream>>>(ybn, se_b, x, br_pw, br_pb, br_pg, br_pbeta,
                                                    mp_pw, mp_pb, mp_g1, mp_b1,
                                                    p3w, p3b, p3g, p3beta, p_b, out);
  k_tc <<<dim3(13, N_),     dim3(256), 0, stream>>>(p_b, x, br_tw, br_tb, br_tg, br_tbeta,
                                                    mp_g2, mp_b2, out);
}

// Round 2
// 1305.257 us; speedup vs baseline: 1.0305x; 1.0305x over previous
//
#include <hip/hip_runtime.h>
#include <hip/hip_bf16.h>
#include <math.h>

#define N_  128
#define C_  64
#define T_  128
#define V_  25
#define S_  3
#define R_  8
#define O_  64
#define BC_ 16
#define TV_ 3200   // T*V

typedef __attribute__((ext_vector_type(8))) short bf16x8;
typedef __attribute__((ext_vector_type(4))) float f32x4;

__device__ inline short f2bf(float f) {            // RNE float->bf16 (finite inputs)
  union { float f; unsigned u; } c; c.f = f;
  unsigned r = (c.u + 0x7FFFu + ((c.u >> 16) & 1u)) >> 16;
  return (short)r;
}
__device__ inline float bf2f(short s) {
  union { float f; unsigned u; } c; c.u = ((unsigned)(unsigned short)s) << 16;
  return c.f;
}

// ---------------- K0: x f32 [n][c][pos] -> xbfT bf16 [n][pos][c]; also c3w->bf16 ----
__global__ __launch_bounds__(256) void k_cvt(const float* __restrict__ x,
                                             const float* __restrict__ c3w,
                                             short* __restrict__ xbfT,
                                             short* __restrict__ c3wbf) {
  int bid = blockIdx.x;                 // 6400 = 128 n * 50 pg
  int n = bid / 50, pg = bid % 50;
  int tid = threadIdx.x, w = tid >> 6, l = tid & 63;   // lane = channel c
  int p0 = pg * 64 + w * 16;
  const float* xp = x + ((size_t)n * 64 + l) * TV_ + p0;
  short* ob = xbfT + ((size_t)n * TV_ + p0) * 64 + l;
  #pragma unroll
  for (int q = 0; q < 4; ++q) {
    float4 xv = *(const float4*)(xp + q * 4);
    ob[(q * 4 + 0) * 64] = f2bf(xv.x);
    ob[(q * 4 + 1) * 64] = f2bf(xv.y);
    ob[(q * 4 + 2) * 64] = f2bf(xv.z);
    ob[(q * 4 + 3) * 64] = f2bf(xv.w);
  }
  if (bid < 144) {                      // 144*256 = 36864 = 3*64*64 c3w elems
    int i = bid * 256 + tid;
    c3wbf[i] = f2bf(c3w[i]);
  }
}

// ---------------- K1: xm[n][c][v] = mean over t ----------------
__global__ __launch_bounds__(256) void k_xm(const float* __restrict__ x,
                                            float* __restrict__ xm) {
  int nc = blockIdx.x;
  const float* xp = x + (size_t)nc * TV_;
  __shared__ float part[250];
  int tid = threadIdx.x;
  if (tid < 250) {
    float s = 0.f;
    for (int k = 0; k < 13; ++k) {
      int idx = tid + 250 * k;
      if (idx < TV_) s += xp[idx];
    }
    part[tid] = s;
  }
  __syncthreads();
  if (tid < 25) {
    float s = 0.f;
    #pragma unroll
    for (int g = 0; g < 10; ++g) s += part[g * 25 + tid];
    xm[(size_t)nc * V_ + tid] = s * (1.0f / 128.0f);
  }
}

// ---------------- K2: affinity -> softmax -> bf16 [n][s][o][u32][v32] (zero-padded) --
__global__ __launch_bounds__(256) void k_aff(
    const float* __restrict__ xm, const float* __restrict__ PA,
    const float* __restrict__ alpha,
    const float* __restrict__ c1w, const float* __restrict__ c1b,
    const float* __restrict__ c2w, const float* __restrict__ c2b,
    const float* __restrict__ c4w, const float* __restrict__ c4b,
    short* __restrict__ affbf) {
  int oq = blockIdx.x, s = blockIdx.y, n = blockIdx.z;
  int tid = threadIdx.x;
  __shared__ float xml[1600];
  __shared__ float w1[512], w2[512], w4l[512];
  __shared__ float x1l[200], x2l[200];
  __shared__ float dift[625 * 9];
  __shared__ float asym[625];
  short* ab = affbf + (((size_t)n * S_ + s) * 64) * 1024;   // [o][u32][v32]
  // zero this block's 16 o-slabs (pads must be 0 for MFMA correctness)
  {
    int4 zz; zz.x = 0; zz.y = 0; zz.z = 0; zz.w = 0;
    int4* z0 = (int4*)(ab + (size_t)(oq * 8) * 1024);
    int4* z1 = (int4*)(ab + (size_t)(oq * 8 + 32) * 1024);
    for (int i = tid; i < 1024; i += 256) { z0[i] = zz; z1[i] = zz; }
  }
  for (int i = tid; i < 1600; i += 256) xml[i] = xm[(size_t)n * 1600 + i];
  for (int i = tid; i < 512; i += 256) {
    w1[i] = c1w[s * 512 + i];
    w2[i] = c2w[s * 512 + i];
    w4l[i] = c4w[s * 512 + i];
  }
  for (int i = tid; i < 625; i += 256) {
    int u = i / 25, v = i % 25;
    asym[i] = PA[s * 625 + u * 25 + v] + PA[s * 625 + v * 25 + u];
  }
  __syncthreads();
  if (tid < 200) {
    int r = tid / 25, v = tid % 25;
    float a1 = c1b[s * R_ + r], a2 = c2b[s * R_ + r];
    #pragma unroll
    for (int c = 0; c < 64; ++c) {
      float xv = xml[c * 25 + v];
      a1 = fmaf(w1[r * 64 + c], xv, a1);
      a2 = fmaf(w2[r * 64 + c], xv, a2);
    }
    x1l[tid] = a1; x2l[tid] = a2;
  }
  __syncthreads();
  for (int i = tid; i < 5000; i += 256) {
    int r = i / 625, rem = i % 625, u = rem / 25, v = rem % 25;
    dift[(u * 25 + v) * 9 + r] = tanhf(x1l[r * 25 + u] - x2l[r * 25 + v]);
  }
  __syncthreads();
  float al = alpha[s];
  if (tid < 200) {
    int ol = tid / 25, v = tid % 25;
    int oA = oq * 8 + ol, oB = oA + 32;
    float avA[25], avB[25];
    float bA = c4b[s * O_ + oA], bB = c4b[s * O_ + oB];
    #pragma unroll
    for (int u = 0; u < 25; ++u) { avA[u] = bA; avB[u] = bB; }
    #pragma unroll
    for (int u = 0; u < 25; ++u) {
      const float* dp = &dift[(u * 25 + v) * 9];
      #pragma unroll
      for (int r = 0; r < 8; ++r) {
        float d = dp[r];
        avA[u] = fmaf(w4l[oA * 8 + r], d, avA[u]);
        avB[u] = fmaf(w4l[oB * 8 + r], d, avB[u]);
      }
    }
    float mA = -1e30f, mB = -1e30f;
    #pragma unroll
    for (int u = 0; u < 25; ++u) {
      float as_ = asym[u * 25 + v];
      avA[u] = fmaf(avA[u], al, as_);
      avB[u] = fmaf(avB[u], al, as_);
      mA = fmaxf(mA, avA[u]); mB = fmaxf(mB, avB[u]);
    }
    float sA = 0.f, sB = 0.f;
    #pragma unroll
    for (int u = 0; u < 25; ++u) {
      avA[u] = expf(avA[u] - mA); sA += avA[u];
      avB[u] = expf(avB[u] - mB); sB += avB[u];
    }
    float iA = 1.0f / sA, iB = 1.0f / sB;
    #pragma unroll
    for (int u = 0; u < 25; ++u) {
      ab[(size_t)oA * 1024 + u * 32 + v] = f2bf(avA[u] * iA);
      ab[(size_t)oB * 1024 + u * 32 + v] = f2bf(avB[u] * iB);
    }
  }
}

// ---------------- K3: x3[nn][s][o][t][v32] = MFMA( c3w[s,o,c], x[n,c,t,v] ) + bias --
// block = (pt 0..49, nn 0..31); wave w owns M-tiles {3w..3w+2} of 12 (rows = s*64+o),
// all 64 pos of the tile. A/B frags straight from global (dense 1KB per frag-load).
__global__ __launch_bounds__(256) void k_gemm1(
    const short* __restrict__ xbfT, const short* __restrict__ c3wbf,
    const float* __restrict__ c3b, short* __restrict__ x3p, int n0) {
  int pt = blockIdx.x;
  int nn = blockIdx.y;
  int n = n0 + nn;
  int tid = threadIdx.x, w = tid >> 6, l = tid & 63;
  int lr = l & 15, lg = l >> 4;
  const short* xb = xbfT + ((size_t)n * TV_ + pt * 64) * 64;
  bf16x8 B[4][2];
  #pragma unroll
  for (int sub = 0; sub < 4; ++sub) {
    const short* rp = xb + (sub * 16 + lr) * 64 + lg * 8;
    B[sub][0] = *(const bf16x8*)(rp);
    B[sub][1] = *(const bf16x8*)(rp + 32);
  }
  bf16x8 A[3][2];
  #pragma unroll
  for (int m = 0; m < 3; ++m) {
    const short* rp = c3wbf + (size_t)((w * 3 + m) * 16 + lr) * 64 + lg * 8;
    A[m][0] = *(const bf16x8*)(rp);
    A[m][1] = *(const bf16x8*)(rp + 32);
  }
  f32x4 acc[3][4];
  #pragma unroll
  for (int m = 0; m < 3; ++m)
    #pragma unroll
    for (int sub = 0; sub < 4; ++sub) acc[m][sub] = (f32x4)(0.f);
  #pragma unroll
  for (int m = 0; m < 3; ++m)
    #pragma unroll
    for (int sub = 0; sub < 4; ++sub) {
      acc[m][sub] = __builtin_amdgcn_mfma_f32_16x16x32_bf16(A[m][0], B[sub][0], acc[m][sub], 0, 0, 0);
      acc[m][sub] = __builtin_amdgcn_mfma_f32_16x16x32_bf16(A[m][1], B[sub][1], acc[m][sub], 0, 0, 0);
    }
  // per-lane (t,v) for the 4 pos columns
  int tl[4], vl[4];
  #pragma unroll
  for (int sub = 0; sub < 4; ++sub) {
    int pos = pt * 64 + sub * 16 + lr;
    tl[sub] = pos / 25; vl[sub] = pos - tl[sub] * 25;
  }
  #pragma unroll
  for (int m = 0; m < 3; ++m) {
    int mt = w * 3 + m;
    #pragma unroll
    for (int j = 0; j < 4; ++j) {
      int r = mt * 16 + lg * 4 + j;          // 0..191 = s*64+o
      float bias = c3b[r];
      short* orow = x3p + (((size_t)nn * 192 + r) * 128) * 32;
      #pragma unroll
      for (int sub = 0; sub < 4; ++sub) {
        orow[tl[sub] * 32 + vl[sub]] = f2bf(acc[m][sub][j] + bias);
      }
    }
  }
}

// ---------------- K4: y = MFMA( x3[t][v32], aff[u32][v32]^T ) + BN; pooled sums ----
// block = (og 0..15, nn 0..31); wave w owns o = og*4+w fully (t=128, u=25).
__global__ __launch_bounds__(256) void k_gemm2(
    const short* __restrict__ x3p, const short* __restrict__ affbf,
    const float* __restrict__ gbn_g, const float* __restrict__ gbn_b,
    short* __restrict__ ybn, float* __restrict__ pooled, int n0) {
  int og = blockIdx.x;
  int nn = blockIdx.y;
  int n = n0 + nn;
  int tid = threadIdx.x, w = tid >> 6, l = tid & 63;
  int lr = l & 15, lg = l >> 4;
  int o = og * 4 + w;
  f32x4 acc[8][2];
  #pragma unroll
  for (int mt = 0; mt < 8; ++mt) { acc[mt][0] = (f32x4)(0.f); acc[mt][1] = (f32x4)(0.f); }
  const short* xb = x3p + (((size_t)nn * 3) * 64 + o) * 4096;     // + s*64*4096
  const short* ab = affbf + (((size_t)n * 3) * 64 + o) * 1024;    // + s*64*1024
  #pragma unroll
  for (int s = 0; s < 3; ++s) {
    const short* abs_ = ab + (size_t)s * 64 * 1024;
    bf16x8 Bf[2];
    Bf[0] = *(const bf16x8*)(abs_ + (0 * 16 + lr) * 32 + lg * 8);
    Bf[1] = *(const bf16x8*)(abs_ + (1 * 16 + lr) * 32 + lg * 8);
    const short* xbs = xb + (size_t)s * 64 * 4096;
    #pragma unroll
    for (int mt = 0; mt < 8; ++mt) {
      bf16x8 Af = *(const bf16x8*)(xbs + (mt * 16 + lr) * 32 + lg * 8);
      acc[mt][0] = __builtin_amdgcn_mfma_f32_16x16x32_bf16(Af, Bf[0], acc[mt][0], 0, 0, 0);
      acc[mt][1] = __builtin_amdgcn_mfma_f32_16x16x32_bf16(Af, Bf[1], acc[mt][1], 0, 0, 0);
    }
  }
  float rs = 1.0f / sqrtf(1.0f + 1e-5f);
  float sc = gbn_g[o] * rs, bb = gbn_b[o];
  short* yb = ybn + ((size_t)n * 64 + o) * TV_;
  float lsum = 0.f;
  #pragma unroll
  for (int mt = 0; mt < 8; ++mt) {
    #pragma unroll
    for (int j = 0; j < 4; ++j) {
      int t = mt * 16 + lg * 4 + j;
      float v0 = fmaf(acc[mt][0][j], sc, bb);          // u = lr < 16
      yb[t * 25 + lr] = f2bf(v0); lsum += v0;
      if (lr < 9) {
        float v1 = fmaf(acc[mt][1][j], sc, bb);        // u = 16 + lr
        yb[t * 25 + 16 + lr] = f2bf(v1); lsum += v1;
      }
    }
  }
  #pragma unroll
  for (int off = 32; off > 0; off >>= 1) lsum += __shfl_down(lsum, off);
  if (l == 0) pooled[(size_t)n * 64 + o] = lsum;
}

// ---------------- K5: squeeze-excite gate ----------------
__global__ __launch_bounds__(64) void k_se(
    const float* __restrict__ pooled,
    const float* __restrict__ att1_w, const float* __restrict__ att1_b,
    const float* __restrict__ att2_w, const float* __restrict__ att2_b,
    float* __restrict__ se) {
  int n = blockIdx.x; int tid = threadIdx.x;
  __shared__ float pl[64]; __shared__ float hbuf[16];
  pl[tid] = pooled[(size_t)n * 64 + tid] * (1.0f / 3200.0f);
  __syncthreads();
  if (tid < 16) {
    float a = att1_b[tid];
    #pragma unroll
    for (int o = 0; o < 64; ++o) a = fmaf(att1_w[tid * 64 + o], pl[o], a);
    hbuf[tid] = fmaxf(a, 0.f);
  }
  __syncthreads();
  float a2 = att2_b[tid];
  #pragma unroll
  for (int k = 0; k < 16; ++k) a2 = fmaf(att2_w[tid * 16 + k], hbuf[k], a2);
  se[(size_t)n * 64 + tid] = 1.0f / (1.0f + expf(-a2));
}

// ---------------- K6: y2 = relu(ybn*se + x); 4x 1x1 convs; branch-3 epilogue ----
__global__ __launch_bounds__(256) void k_pw(
    const short* __restrict__ ybn, const float* __restrict__ se,
    const float* __restrict__ x,
    const float* __restrict__ br_pw, const float* __restrict__ br_pb,
    const float* __restrict__ br_pg, const float* __restrict__ br_pbeta,
    const float* __restrict__ mp_pw, const float* __restrict__ mp_pb,
    const float* __restrict__ mp_g1, const float* __restrict__ mp_b1,
    const float* __restrict__ p3w, const float* __restrict__ p3b,
    const float* __restrict__ p3g, const float* __restrict__ p3beta,
    short* __restrict__ pbuf, float* __restrict__ outp) {
  int tt = blockIdx.x; int n = blockIdx.y;
  int t0 = tt * 10;
  int npos = min(10, T_ - t0) * 25;
  int tid = threadIdx.x;
  if (tid >= npos) return;
  float rs = 1.0f / sqrtf(1.0f + 1e-5f);
  size_t base = (size_t)n * C_ * TV_ + (size_t)t0 * 25 + tid;
  const float* sep = se + (size_t)n * 64;
  float y2[64]; float xhi[16];
  #pragma unroll
  for (int o = 0; o < 64; ++o) {
    float xv = x[base + (size_t)o * TV_];
    float yv = bf2f(ybn[base + (size_t)o * TV_]);
    y2[o] = fmaxf(fmaf(yv, sep[o], xv), 0.f);
    if (o >= 48) xhi[o - 48] = xv;
  }
  #pragma unroll
  for (int h = 0; h < 3; ++h) {
    const float* wp = (h == 0) ? br_pw : (h == 1) ? (br_pw + 1024) : mp_pw;
    short* po = pbuf + (((size_t)h * N_ + n) * 16) * TV_ + (size_t)t0 * 25 + tid;
    #pragma unroll
    for (int bc = 0; bc < 16; ++bc) {
      float g, beta, pb;
      if (h < 2) { g = br_pg[h * 16 + bc]; beta = br_pbeta[h * 16 + bc]; pb = br_pb[h * 16 + bc]; }
      else       { g = mp_g1[bc];          beta = mp_b1[bc];             pb = mp_pb[bc]; }
      float a = 0.f;
      #pragma unroll
      for (int o = 0; o < 64; ++o) a = fmaf(wp[bc * 64 + o], y2[o], a);
      po[(size_t)bc * TV_] = f2bf(fmaxf(fmaf(a + pb, g * rs, beta), 0.f));
    }
  }
  #pragma unroll
  for (int bc = 0; bc < 16; ++bc) {
    float a = 0.f;
    #pragma unroll
    for (int o = 0; o < 64; ++o) a = fmaf(p3w[bc * 64 + o], y2[o], a);
    float ov = fmaf(a + p3b[bc], p3g[bc] * rs, p3beta[bc]);   // no relu (branch 3)
    outp[base + (size_t)(48 + bc) * TV_] = fmaxf(ov + xhi[bc], 0.f);
  }
}

// ---------------- K7: temporal convs + maxpool + BN + residual + relu ----------
__global__ __launch_bounds__(256) void k_tc(
    const short* __restrict__ pbuf, const float* __restrict__ x,
    const float* __restrict__ br_tw, const float* __restrict__ br_tb,
    const float* __restrict__ br_tg, const float* __restrict__ br_tbeta,
    const float* __restrict__ mp_g2, const float* __restrict__ mp_b2,
    float* __restrict__ outp) {
  int tt = blockIdx.x; int n = blockIdx.y;
  int t0 = tt * 10;
  int npos = min(10, T_ - t0) * 25;
  int tid = threadIdx.x;
  if (tid >= npos) return;
  int tl = tid / 25, v = tid % 25;
  int t = t0 + tl;
  float rs = 1.0f / sqrtf(1.0f + 1e-5f);
  size_t xbase = (size_t)n * C_ * TV_ + (size_t)t * 25 + v;
  #pragma unroll
  for (int h = 0; h < 2; ++h) {
    int d = 1 + h;
    const short* pp = pbuf + (((size_t)h * N_ + n) * 16) * TV_ + v;
    float acc[16];
    #pragma unroll
    for (int bc = 0; bc < 16; ++bc) acc[bc] = 0.f;
    #pragma unroll
    for (int ic = 0; ic < 16; ++ic) {
      float tap[5];
      #pragma unroll
      for (int k = 0; k < 5; ++k) {
        int ts = t + (k - 2) * d;
        tap[k] = (ts >= 0 && ts < T_) ? bf2f(pp[(size_t)ic * TV_ + ts * 25]) : 0.f;
      }
      #pragma unroll
      for (int bc = 0; bc < 16; ++bc) {
        #pragma unroll
        for (int k = 0; k < 5; ++k)
          acc[bc] = fmaf(br_tw[((h * 16 + bc) * 16 + ic) * 5 + k], tap[k], acc[bc]);
      }
    }
    #pragma unroll
    for (int bc = 0; bc < 16; ++bc) {
      float sc  = br_tg[h * 16 + bc] * rs;
      float val = fmaf(acc[bc] + br_tb[h * 16 + bc], sc, br_tbeta[h * 16 + bc]);
      int ch = h * 16 + bc;
      float xv = x[xbase + (size_t)ch * TV_];
      outp[xbase + (size_t)ch * TV_] = fmaxf(val + xv, 0.f);
    }
  }
  {
    const short* pp = pbuf + (((size_t)2 * N_ + n) * 16) * TV_ + v;
    #pragma unroll
    for (int ic = 0; ic < 16; ++ic) {
      float m = bf2f(pp[(size_t)ic * TV_ + t * 25]);
      if (t > 0)      m = fmaxf(m, bf2f(pp[(size_t)ic * TV_ + (t - 1) * 25]));
      if (t < T_ - 1) m = fmaxf(m, bf2f(pp[(size_t)ic * TV_ + (t + 1) * 25]));
      float val = fmaf(m, mp_g2[ic] * rs, mp_b2[ic]);
      int ch = 32 + ic;
      float xv = x[xbase + (size_t)ch * TV_];
      outp[xbase + (size_t)ch * TV_] = fmaxf(val + xv, 0.f);
    }
  }
}

extern "C" void kernel_launch(void* const* d_in, const int* in_sizes, int n_in,
                              void* d_out, int out_size, void* d_ws, size_t ws_size,
                              hipStream_t stream) {
  (void)in_sizes; (void)n_in; (void)out_size; (void)ws_size;
  const float* x      = (const float*)d_in[0];
  const float* PA     = (const float*)d_in[1];
  const float* alpha  = (const float*)d_in[2];
  const float* c1w    = (const float*)d_in[3];
  const float* c1b    = (const float*)d_in[4];
  const float* c2w    = (const float*)d_in[5];
  const float* c2b    = (const float*)d_in[6];
  const float* c3w    = (const float*)d_in[7];
  const float* c3b    = (const float*)d_in[8];
  const float* c4w    = (const float*)d_in[9];
  const float* c4b    = (const float*)d_in[10];
  const float* gbn_g  = (const float*)d_in[11];
  const float* gbn_b  = (const float*)d_in[12];
  const float* att1_w = (const float*)d_in[13];
  const float* att1_b = (const float*)d_in[14];
  const float* att2_w = (const float*)d_in[15];
  const float* att2_b = (const float*)d_in[16];
  const float* br_pw  = (const float*)d_in[17];
  const float* br_pb  = (const float*)d_in[18];
  const float* br_pg  = (const float*)d_in[19];
  const float* br_pbeta = (const float*)d_in[20];
  const float* br_tw  = (const float*)d_in[21];
  const float* br_tb  = (const float*)d_in[22];
  const float* br_tg  = (const float*)d_in[23];
  const float* br_tbeta = (const float*)d_in[24];
  const float* mp_pw  = (const float*)d_in[25];
  const float* mp_pb  = (const float*)d_in[26];
  const float* mp_g1  = (const float*)d_in[27];
  const float* mp_b1  = (const float*)d_in[28];
  const float* mp_g2  = (const float*)d_in[29];
  const float* mp_b2  = (const float*)d_in[30];
  const float* p3w    = (const float*)d_in[31];
  const float* p3b    = (const float*)d_in[32];
  const float* p3g    = (const float*)d_in[33];
  const float* p3beta = (const float*)d_in[34];
  float* out = (float*)d_out;
  float* ws  = (float*)d_ws;

  // ws layout (float units, all 16B-aligned):
  float* xm_b    = ws;                                //   204,800 f32
  float* pooled  = ws + 204800;                       //     8,192 f32
  float* se_b    = ws + 212992;                       //     8,192 f32
  short* xbfT    = (short*)(ws + 221184);             // 26,214,400 bf16
  short* affbf   = (short*)(ws + 13328384);           // 25,165,824 bf16 [n][s][o][32u][32v]
  short* x3p     = (short*)(ws + 25911296);           // 25,165,824 bf16 (32-n chunk)
  short* ybn     = (short*)(ws + 38494208);           // 26,214,400 bf16
  short* c3wbf   = (short*)(ws + 51601408);           //    36,864 bf16   (end ~206.5MB)
  short* p_b     = (short*)(ws + 13328384);           // 19,660,800 bf16 (overlays affbf; dead by then)

  k_cvt<<<dim3(6400),        dim3(256), 0, stream>>>(x, c3w, xbfT, c3wbf);
  k_xm <<<dim3(N_ * C_),     dim3(256), 0, stream>>>(x, xm_b);
  k_aff<<<dim3(4, 3, N_),    dim3(256), 0, stream>>>(xm_b, PA, alpha, c1w, c1b, c2w, c2b,
                                                     c4w, c4b, affbf);
  for (int ch = 0; ch < 4; ++ch) {
    k_gemm1<<<dim3(50, 32), dim3(256), 0, stream>>>(xbfT, c3wbf, c3b, x3p, ch * 32);
    k_gemm2<<<dim3(16, 32), dim3(256), 0, stream>>>(x3p, affbf, gbn_g, gbn_b, ybn, pooled, ch * 32);
  }
  k_se <<<dim3(N_),          dim3(64),  0, stream>>>(pooled, att1_w, att1_b, att2_w, att2_b, se_b);
  k_pw <<<dim3(13, N_),      dim3(256), 0, stream>>>(ybn, se_b, x, br_pw, br_pb, br_pg, br_pbeta,
                                                     mp_pw, mp_pb, mp_g1, mp_b1,
                                                     p3w, p3b, p3g, p3beta, p_b, out);
  k_tc <<<dim3(13, N_),      dim3(256), 0, stream>>>(p_b, x, br_tw, br_tb, br_tg, br_tbeta,
                                                     mp_g2, mp_b2, out);
}

// Round 4
// 671.297 us; speedup vs baseline: 2.0037x; 1.9444x over previous
//
#include <hip/hip_runtime.h>
#include <hip/hip_bf16.h>
#include <math.h>

#define N_  128
#define C_  64
#define T_  128
#define V_  25
#define S_  3
#define R_  8
#define O_  64
#define BC_ 16
#define TV_ 3200   // T*V

typedef __attribute__((ext_vector_type(8))) short bf16x8;
typedef __attribute__((ext_vector_type(4))) float f32x4;

__device__ inline short f2bf(float f) {            // RNE float->bf16 (finite inputs)
  union { float f; unsigned u; } c; c.f = f;
  unsigned r = (c.u + 0x7FFFu + ((c.u >> 16) & 1u)) >> 16;
  return (short)r;
}
__device__ inline float bf2f(short s) {
  union { float f; unsigned u; } c; c.u = ((unsigned)(unsigned short)s) << 16;
  return c.f;
}

// ---------------- K0: x f32 [n][c][pos] -> xbfT bf16 [n][pos][c]; c3w->bf16;
//                  bid==6400: temporal-weight prep w2g[plane][h][bc][96] (K zero-pad) --
__global__ __launch_bounds__(256) void k_cvt(const float* __restrict__ x,
                                             const float* __restrict__ c3w,
                                             const float* __restrict__ br_tw,
                                             short* __restrict__ xbfT,
                                             short* __restrict__ c3wbf,
                                             short* __restrict__ w2g) {
  int bid = blockIdx.x;                 // 6400 = 128 n * 50 pg, +1 prep block
  int tid = threadIdx.x;
  if (bid < 6400) {
    int n = bid / 50, pg = bid % 50;
    int w = tid >> 6, l = tid & 63;     // lane = channel c
    int p0 = pg * 64 + w * 16;
    const float* xp = x + ((size_t)n * 64 + l) * TV_ + p0;
    short* ob = xbfT + ((size_t)n * TV_ + p0) * 64 + l;
    #pragma unroll
    for (int q = 0; q < 4; ++q) {
      float4 xv = *(const float4*)(xp + q * 4);
      ob[(q * 4 + 0) * 64] = f2bf(xv.x);
      ob[(q * 4 + 1) * 64] = f2bf(xv.y);
      ob[(q * 4 + 2) * 64] = f2bf(xv.z);
      ob[(q * 4 + 3) * 64] = f2bf(xv.w);
    }
    if (bid < 144) {                    // 144*256 = 36864 = 3*64*64 c3w elems
      int i = bid * 256 + tid;
      c3wbf[i] = f2bf(c3w[i]);
    }
  } else {
    // w2g: plane0 = bf(W), plane1 = bf(W - f32(bf(W))); kidx = ktap*16+ic, pad to 96
    for (int i = tid; i < 6144; i += 256) {
      int plane = i / 3072, rem = i % 3072;
      int h = rem / 1536, rem2 = rem % 1536;
      int bc = rem2 / 96, kidx = rem2 % 96;
      short outv = 0;
      if (kidx < 80) {
        int ktap = kidx >> 4, ic = kidx & 15;
        float wv = br_tw[((h * 16 + bc) * 16 + ic) * 5 + ktap];
        short wb = f2bf(wv);
        outv = (plane == 0) ? wb : f2bf(wv - bf2f(wb));
      }
      w2g[i] = outv;
    }
  }
}

// ---------------- K1: xm[n][c][v] = mean over t ----------------
__global__ __launch_bounds__(256) void k_xm(const float* __restrict__ x,
                                            float* __restrict__ xm) {
  int nc = blockIdx.x;
  const float* xp = x + (size_t)nc * TV_;
  __shared__ float part[250];
  int tid = threadIdx.x;
  if (tid < 250) {
    float s = 0.f;
    for (int k = 0; k < 13; ++k) {
      int idx = tid + 250 * k;
      if (idx < TV_) s += xp[idx];
    }
    part[tid] = s;
  }
  __syncthreads();
  if (tid < 25) {
    float s = 0.f;
    #pragma unroll
    for (int g = 0; g < 10; ++g) s += part[g * 25 + tid];
    xm[(size_t)nc * V_ + tid] = s * (1.0f / 128.0f);
  }
}

// ---------------- K2: affinity -> softmax -> bf16 [n][s][o][u32][v32] (zero-padded) --
__global__ __launch_bounds__(256) void k_aff(
    const float* __restrict__ xm, const float* __restrict__ PA,
    const float* __restrict__ alpha,
    const float* __restrict__ c1w, const float* __restrict__ c1b,
    const float* __restrict__ c2w, const float* __restrict__ c2b,
    const float* __restrict__ c4w, const float* __restrict__ c4b,
    short* __restrict__ affbf) {
  int oq = blockIdx.x, s = blockIdx.y, n = blockIdx.z;
  int tid = threadIdx.x;
  __shared__ float xml[1600];
  __shared__ float w1[512], w2[512], w4l[512];
  __shared__ float x1l[200], x2l[200];
  __shared__ float dift[625 * 9];
  __shared__ float asym[625];
  short* ab = affbf + (((size_t)n * S_ + s) * 64) * 1024;   // [o][u32][v32]
  {
    int4 zz; zz.x = 0; zz.y = 0; zz.z = 0; zz.w = 0;
    int4* z0 = (int4*)(ab + (size_t)(oq * 8) * 1024);
    int4* z1 = (int4*)(ab + (size_t)(oq * 8 + 32) * 1024);
    for (int i = tid; i < 1024; i += 256) { z0[i] = zz; z1[i] = zz; }
  }
  for (int i = tid; i < 1600; i += 256) xml[i] = xm[(size_t)n * 1600 + i];
  for (int i = tid; i < 512; i += 256) {
    w1[i] = c1w[s * 512 + i];
    w2[i] = c2w[s * 512 + i];
    w4l[i] = c4w[s * 512 + i];
  }
  for (int i = tid; i < 625; i += 256) {
    int u = i / 25, v = i % 25;
    asym[i] = PA[s * 625 + u * 25 + v] + PA[s * 625 + v * 25 + u];
  }
  __syncthreads();
  if (tid < 200) {
    int r = tid / 25, v = tid % 25;
    float a1 = c1b[s * R_ + r], a2 = c2b[s * R_ + r];
    #pragma unroll
    for (int c = 0; c < 64; ++c) {
      float xv = xml[c * 25 + v];
      a1 = fmaf(w1[r * 64 + c], xv, a1);
      a2 = fmaf(w2[r * 64 + c], xv, a2);
    }
    x1l[tid] = a1; x2l[tid] = a2;
  }
  __syncthreads();
  for (int i = tid; i < 5000; i += 256) {
    int r = i / 625, rem = i % 625, u = rem / 25, v = rem % 25;
    dift[(u * 25 + v) * 9 + r] = tanhf(x1l[r * 25 + u] - x2l[r * 25 + v]);
  }
  __syncthreads();
  float al = alpha[s];
  if (tid < 200) {
    int ol = tid / 25, v = tid % 25;
    int oA = oq * 8 + ol, oB = oA + 32;
    float avA[25], avB[25];
    float bA = c4b[s * O_ + oA], bB = c4b[s * O_ + oB];
    #pragma unroll
    for (int u = 0; u < 25; ++u) { avA[u] = bA; avB[u] = bB; }
    #pragma unroll
    for (int u = 0; u < 25; ++u) {
      const float* dp = &dift[(u * 25 + v) * 9];
      #pragma unroll
      for (int r = 0; r < 8; ++r) {
        float d = dp[r];
        avA[u] = fmaf(w4l[oA * 8 + r], d, avA[u]);
        avB[u] = fmaf(w4l[oB * 8 + r], d, avB[u]);
      }
    }
    float mA = -1e30f, mB = -1e30f;
    #pragma unroll
    for (int u = 0; u < 25; ++u) {
      float as_ = asym[u * 25 + v];
      avA[u] = fmaf(avA[u], al, as_);
      avB[u] = fmaf(avB[u], al, as_);
      mA = fmaxf(mA, avA[u]); mB = fmaxf(mB, avB[u]);
    }
    float sA = 0.f, sB = 0.f;
    #pragma unroll
    for (int u = 0; u < 25; ++u) {
      avA[u] = expf(avA[u] - mA); sA += avA[u];
      avB[u] = expf(avB[u] - mB); sB += avB[u];
    }
    float iA = 1.0f / sA, iB = 1.0f / sB;
    #pragma unroll
    for (int u = 0; u < 25; ++u) {
      ab[(size_t)oA * 1024 + u * 32 + v] = f2bf(avA[u] * iA);
      ab[(size_t)oB * 1024 + u * 32 + v] = f2bf(avB[u] * iB);
    }
  }
}

// ---------------- K3: x3[nn][s][o][t][v32] = MFMA( c3w[s,o,c], x[n,c,t,v] ) + bias --
__global__ __launch_bounds__(256) void k_gemm1(
    const short* __restrict__ xbfT, const short* __restrict__ c3wbf,
    const float* __restrict__ c3b, short* __restrict__ x3p, int n0) {
  int pt = blockIdx.x;
  int nn = blockIdx.y;
  int n = n0 + nn;
  int tid = threadIdx.x, w = tid >> 6, l = tid & 63;
  int lr = l & 15, lg = l >> 4;
  const short* xb = xbfT + ((size_t)n * TV_ + pt * 64) * 64;
  bf16x8 B[4][2];
  #pragma unroll
  for (int sub = 0; sub < 4; ++sub) {
    const short* rp = xb + (sub * 16 + lr) * 64 + lg * 8;
    B[sub][0] = *(const bf16x8*)(rp);
    B[sub][1] = *(const bf16x8*)(rp + 32);
  }
  bf16x8 A[3][2];
  #pragma unroll
  for (int m = 0; m < 3; ++m) {
    const short* rp = c3wbf + (size_t)((w * 3 + m) * 16 + lr) * 64 + lg * 8;
    A[m][0] = *(const bf16x8*)(rp);
    A[m][1] = *(const bf16x8*)(rp + 32);
  }
  f32x4 acc[3][4];
  #pragma unroll
  for (int m = 0; m < 3; ++m)
    #pragma unroll
    for (int sub = 0; sub < 4; ++sub) acc[m][sub] = (f32x4)(0.f);
  #pragma unroll
  for (int m = 0; m < 3; ++m)
    #pragma unroll
    for (int sub = 0; sub < 4; ++sub) {
      acc[m][sub] = __builtin_amdgcn_mfma_f32_16x16x32_bf16(A[m][0], B[sub][0], acc[m][sub], 0, 0, 0);
      acc[m][sub] = __builtin_amdgcn_mfma_f32_16x16x32_bf16(A[m][1], B[sub][1], acc[m][sub], 0, 0, 0);
    }
  int tl[4], vl[4];
  #pragma unroll
  for (int sub = 0; sub < 4; ++sub) {
    int pos = pt * 64 + sub * 16 + lr;
    tl[sub] = pos / 25; vl[sub] = pos - tl[sub] * 25;
  }
  #pragma unroll
  for (int m = 0; m < 3; ++m) {
    int mt = w * 3 + m;
    #pragma unroll
    for (int j = 0; j < 4; ++j) {
      int r = mt * 16 + lg * 4 + j;          // 0..191 = s*64+o
      float bias = c3b[r];
      short* orow = x3p + (((size_t)nn * 192 + r) * 128) * 32;
      #pragma unroll
      for (int sub = 0; sub < 4; ++sub) {
        orow[tl[sub] * 32 + vl[sub]] = f2bf(acc[m][sub][j] + bias);
      }
    }
  }
}

// ---------------- K4: y = MFMA( x3[t][v32], aff[u32][v32]^T ) + BN; pooled sums ----
__global__ __launch_bounds__(256) void k_gemm2(
    const short* __restrict__ x3p, const short* __restrict__ affbf,
    const float* __restrict__ gbn_g, const float* __restrict__ gbn_b,
    short* __restrict__ ybn, float* __restrict__ pooled, int n0) {
  int og = blockIdx.x;
  int nn = blockIdx.y;
  int n = n0 + nn;
  int tid = threadIdx.x, w = tid >> 6, l = tid & 63;
  int lr = l & 15, lg = l >> 4;
  int o = og * 4 + w;
  f32x4 acc[8][2];
  #pragma unroll
  for (int mt = 0; mt < 8; ++mt) { acc[mt][0] = (f32x4)(0.f); acc[mt][1] = (f32x4)(0.f); }
  const short* xb = x3p + (((size_t)nn * 3) * 64 + o) * 4096;
  const short* ab = affbf + (((size_t)n * 3) * 64 + o) * 1024;
  #pragma unroll
  for (int s = 0; s < 3; ++s) {
    const short* abs_ = ab + (size_t)s * 64 * 1024;
    bf16x8 Bf[2];
    Bf[0] = *(const bf16x8*)(abs_ + (0 * 16 + lr) * 32 + lg * 8);
    Bf[1] = *(const bf16x8*)(abs_ + (1 * 16 + lr) * 32 + lg * 8);
    const short* xbs = xb + (size_t)s * 64 * 4096;
    #pragma unroll
    for (int mt = 0; mt < 8; ++mt) {
      bf16x8 Af = *(const bf16x8*)(xbs + (mt * 16 + lr) * 32 + lg * 8);
      acc[mt][0] = __builtin_amdgcn_mfma_f32_16x16x32_bf16(Af, Bf[0], acc[mt][0], 0, 0, 0);
      acc[mt][1] = __builtin_amdgcn_mfma_f32_16x16x32_bf16(Af, Bf[1], acc[mt][1], 0, 0, 0);
    }
  }
  float rs = 1.0f / sqrtf(1.0f + 1e-5f);
  float sc = gbn_g[o] * rs, bb = gbn_b[o];
  short* yb = ybn + ((size_t)n * 64 + o) * TV_;
  float lsum = 0.f;
  #pragma unroll
  for (int mt = 0; mt < 8; ++mt) {
    #pragma unroll
    for (int j = 0; j < 4; ++j) {
      int t = mt * 16 + lg * 4 + j;
      float v0 = fmaf(acc[mt][0][j], sc, bb);          // u = lr < 16
      yb[t * 25 + lr] = f2bf(v0); lsum += v0;
      if (lr < 9) {
        float v1 = fmaf(acc[mt][1][j], sc, bb);        // u = 16 + lr
        yb[t * 25 + 16 + lr] = f2bf(v1); lsum += v1;
      }
    }
  }
  #pragma unroll
  for (int off = 32; off > 0; off >>= 1) lsum += __shfl_down(lsum, off);
  if (l == 0) pooled[(size_t)n * 64 + o] = lsum;
}

// ---------------- K5: squeeze-excite gate ----------------
__global__ __launch_bounds__(64) void k_se(
    const float* __restrict__ pooled,
    const float* __restrict__ att1_w, const float* __restrict__ att1_b,
    const float* __restrict__ att2_w, const float* __restrict__ att2_b,
    float* __restrict__ se) {
  int n = blockIdx.x; int tid = threadIdx.x;
  __shared__ float pl[64]; __shared__ float hbuf[16];
  pl[tid] = pooled[(size_t)n * 64 + tid] * (1.0f / 3200.0f);
  __syncthreads();
  if (tid < 16) {
    float a = att1_b[tid];
    #pragma unroll
    for (int o = 0; o < 64; ++o) a = fmaf(att1_w[tid * 64 + o], pl[o], a);
    hbuf[tid] = fmaxf(a, 0.f);
  }
  __syncthreads();
  float a2 = att2_b[tid];
  #pragma unroll
  for (int k = 0; k < 16; ++k) a2 = fmaf(att2_w[tid * 16 + k], hbuf[k], a2);
  se[(size_t)n * 64 + tid] = 1.0f / (1.0f + expf(-a2));
}

// ---------------- K6: y2 = relu(ybn*se + x); 4x 1x1 convs; branch-3 epilogue ----
// pbuf layout: [h][n][t][v][ic16] bf16 (channel-innermost for k_tcm/k_mp)
__global__ __launch_bounds__(256) void k_pw(
    const short* __restrict__ ybn, const float* __restrict__ se,
    const float* __restrict__ x,
    const float* __restrict__ br_pw, const float* __restrict__ br_pb,
    const float* __restrict__ br_pg, const float* __restrict__ br_pbeta,
    const float* __restrict__ mp_pw, const float* __restrict__ mp_pb,
    const float* __restrict__ mp_g1, const float* __restrict__ mp_b1,
    const float* __restrict__ p3w, const float* __restrict__ p3b,
    const float* __restrict__ p3g, const float* __restrict__ p3beta,
    short* __restrict__ pbuf, float* __restrict__ outp) {
  int tt = blockIdx.x; int n = blockIdx.y;
  int t0 = tt * 10;
  int npos = min(10, T_ - t0) * 25;
  int tid = threadIdx.x;
  if (tid >= npos) return;
  float rs = 1.0f / sqrtf(1.0f + 1e-5f);
  size_t base = (size_t)n * C_ * TV_ + (size_t)t0 * 25 + tid;
  int pos = t0 * 25 + tid;
  const float* sep = se + (size_t)n * 64;
  float y2[64]; float xhi[16];
  #pragma unroll
  for (int o = 0; o < 64; ++o) {
    float xv = x[base + (size_t)o * TV_];
    float yv = bf2f(ybn[base + (size_t)o * TV_]);
    y2[o] = fmaxf(fmaf(yv, sep[o], xv), 0.f);
    if (o >= 48) xhi[o - 48] = xv;
  }
  #pragma unroll
  for (int h = 0; h < 3; ++h) {
    const float* wp = (h == 0) ? br_pw : (h == 1) ? (br_pw + 1024) : mp_pw;
    short* po = pbuf + ((size_t)(h * N_ + n) * TV_ + pos) * 16;
    bf16x8 v0, v1;
    #pragma unroll
    for (int bc = 0; bc < 16; ++bc) {
      float g, beta, pb;
      if (h < 2) { g = br_pg[h * 16 + bc]; beta = br_pbeta[h * 16 + bc]; pb = br_pb[h * 16 + bc]; }
      else       { g = mp_g1[bc];          beta = mp_b1[bc];             pb = mp_pb[bc]; }
      float a = 0.f;
      #pragma unroll
      for (int o = 0; o < 64; ++o) a = fmaf(wp[bc * 64 + o], y2[o], a);
      short pk = f2bf(fmaxf(fmaf(a + pb, g * rs, beta), 0.f));
      if (bc < 8) v0[bc] = pk; else v1[bc - 8] = pk;
    }
    *(bf16x8*)(po) = v0;
    *(bf16x8*)(po + 8) = v1;
  }
  #pragma unroll
  for (int bc = 0; bc < 16; ++bc) {
    float a = 0.f;
    #pragma unroll
    for (int o = 0; o < 64; ++o) a = fmaf(p3w[bc * 64 + o], y2[o], a);
    float ov = fmaf(a + p3b[bc], p3g[bc] * rs, p3beta[bc]);   // no relu (branch 3)
    outp[base + (size_t)(48 + bc) * TV_] = fmaxf(ov + xhi[bc], 0.f);
  }
}

// ---------------- K7: temporal conv via MFMA (im2col over LDS tile) --------------
// block = (tt 0..1, h 0..1, n); wave handles N-tiles of 16 pos; K = 80 pad 96.
// out[bc][pos] = sum_{ic,ktap} W2[bc][ktap*16+ic] * p[ic][t+(ktap-2)d][v]
__global__ __launch_bounds__(256) void k_tcm(
    const short* __restrict__ pbuf, const short* __restrict__ w2g,
    const float* __restrict__ x,
    const float* __restrict__ br_tb, const float* __restrict__ br_tg,
    const float* __restrict__ br_tbeta,
    float* __restrict__ outp) {
  int tt = blockIdx.x, h = blockIdx.y, n = blockIdx.z;
  int d = 1 + h;
  int tid = threadIdx.x, w = tid >> 6, l = tid & 63;
  int lr = l & 15, lg = l >> 4;
  __shared__ short ptile[72 * 25 * 16];   // 57,600 B: rows t0-4 .. t0+67 (zero halo)
  {
    const int4* src = (const int4*)(pbuf + ((size_t)(h * N_ + n) * TV_) * 16);
    int4* dst = (int4*)ptile;
    int4 zz; zz.x = 0; zz.y = 0; zz.z = 0; zz.w = 0;
    for (int u = tid; u < 3600; u += 256) {      // 72 rows x 50 int4/row
      int r = u / 50, q = u - r * 50;
      int t = tt * 64 - 4 + r;
      dst[u] = (t >= 0 && t < T_) ? src[t * 50 + q] : zz;
    }
  }
  // A-frags: plane (0=bf(W),1=residual) x ks; row = lr(bc), k = ks*32+lg*8
  bf16x8 Af0[3], Af1[3];
  #pragma unroll
  for (int ks = 0; ks < 3; ++ks) {
    Af0[ks] = *(const bf16x8*)(w2g + ((0 * 2 + h) * 16 + lr) * 96 + ks * 32 + lg * 8);
    Af1[ks] = *(const bf16x8*)(w2g + ((1 * 2 + h) * 16 + lr) * 96 + ks * 32 + lg * 8);
  }
  // BN constants per output row bc = lg*4+j: val = acc*scl + shf
  float rs = 1.0f / sqrtf(1.0f + 1e-5f);
  float scl[4], shf[4];
  #pragma unroll
  for (int j = 0; j < 4; ++j) {
    int bc = lg * 4 + j;
    float sc = br_tg[h * 16 + bc] * rs;
    scl[j] = sc;
    shf[j] = fmaf(br_tb[h * 16 + bc], sc, br_tbeta[h * 16 + bc]);
  }
  __syncthreads();
  for (int nt = w; nt < 100; nt += 4) {
    int posL = nt * 16 + lr;                     // 0..1599 within tile
    int tL = posL / 25, v = posL - tL * 25;
    f32x4 acc = (f32x4)(0.f);
    #pragma unroll
    for (int ks = 0; ks < 3; ++ks) {
      int ktap = 2 * ks + (lg >> 1);             // 0..5 (5 = zero-weight pad)
      int ic0 = (lg & 1) * 8;
      int r = tL + 4 + (ktap - 2) * d;
      r = min(r, 71);                            // clamp pad-tap address
      bf16x8 Bf = *(const bf16x8*)(ptile + (r * 25 + v) * 16 + ic0);
      acc = __builtin_amdgcn_mfma_f32_16x16x32_bf16(Af0[ks], Bf, acc, 0, 0, 0);
      acc = __builtin_amdgcn_mfma_f32_16x16x32_bf16(Af1[ks], Bf, acc, 0, 0, 0);
    }
    int gpos = tt * 1600 + posL;
    #pragma unroll
    for (int j = 0; j < 4; ++j) {
      int ch = h * 16 + lg * 4 + j;
      size_t oa = ((size_t)n * 64 + ch) * TV_ + gpos;
      float xv = x[oa];
      outp[oa] = fmaxf(fmaf(acc[j], scl[j], shf[j]) + xv, 0.f);
    }
  }
}

// ---------------- K8: maxpool branch + BN + residual + relu ----------------
__global__ __launch_bounds__(256) void k_mp(
    const short* __restrict__ pbuf, const float* __restrict__ x,
    const float* __restrict__ mp_g2, const float* __restrict__ mp_b2,
    float* __restrict__ outp) {
  int tt = blockIdx.x, n = blockIdx.y;
  int t0 = tt * 10;
  int npos = min(10, T_ - t0) * 25;
  int tid = threadIdx.x;
  if (tid >= npos) return;
  int pos = t0 * 25 + tid;
  int t = pos / 25, v = pos - t * 25;
  const short* pb = pbuf + ((size_t)(2 * N_ + n) * TV_) * 16;
  int tm = max(t - 1, 0), tp = min(t + 1, T_ - 1);
  bf16x8 a0 = *(const bf16x8*)(pb + (tm * 25 + v) * 16);
  bf16x8 a1 = *(const bf16x8*)(pb + (tm * 25 + v) * 16 + 8);
  bf16x8 b0 = *(const bf16x8*)(pb + (t  * 25 + v) * 16);
  bf16x8 b1 = *(const bf16x8*)(pb + (t  * 25 + v) * 16 + 8);
  bf16x8 c0 = *(const bf16x8*)(pb + (tp * 25 + v) * 16);
  bf16x8 c1 = *(const bf16x8*)(pb + (tp * 25 + v) * 16 + 8);
  float rs = 1.0f / sqrtf(1.0f + 1e-5f);
  #pragma unroll
  for (int i = 0; i < 8; ++i) {
    float m0 = fmaxf(fmaxf(bf2f(a0[i]), bf2f(b0[i])), bf2f(c0[i]));
    float m1 = fmaxf(fmaxf(bf2f(a1[i]), bf2f(b1[i])), bf2f(c1[i]));
    size_t oa0 = ((size_t)n * 64 + 32 + i) * TV_ + pos;
    size_t oa1 = ((size_t)n * 64 + 40 + i) * TV_ + pos;
    float v0 = fmaf(m0, mp_g2[i] * rs, mp_b2[i]);
    float v1 = fmaf(m1, mp_g2[8 + i] * rs, mp_b2[8 + i]);
    outp[oa0] = fmaxf(v0 + x[oa0], 0.f);
    outp[oa1] = fmaxf(v1 + x[oa1], 0.f);
  }
}

extern "C" void kernel_launch(void* const* d_in, const int* in_sizes, int n_in,
                              void* d_out, int out_size, void* d_ws, size_t ws_size,
                              hipStream_t stream) {
  (void)in_sizes; (void)n_in; (void)out_size; (void)ws_size;
  const float* x      = (const float*)d_in[0];
  const float* PA     = (const float*)d_in[1];
  const float* alpha  = (const float*)d_in[2];
  const float* c1w    = (const float*)d_in[3];
  const float* c1b    = (const float*)d_in[4];
  const float* c2w    = (const float*)d_in[5];
  const float* c2b    = (const float*)d_in[6];
  const float* c3w    = (const float*)d_in[7];
  const float* c3b    = (const float*)d_in[8];
  const float* c4w    = (const float*)d_in[9];
  const float* c4b    = (const float*)d_in[10];
  const float* gbn_g  = (const float*)d_in[11];
  const float* gbn_b  = (const float*)d_in[12];
  const float* att1_w = (const float*)d_in[13];
  const float* att1_b = (const float*)d_in[14];
  const float* att2_w = (const float*)d_in[15];
  const float* att2_b = (const float*)d_in[16];
  const float* br_pw  = (const float*)d_in[17];
  const float* br_pb  = (const float*)d_in[18];
  const float* br_pg  = (const float*)d_in[19];
  const float* br_pbeta = (const float*)d_in[20];
  const float* br_tw  = (const float*)d_in[21];
  const float* br_tb  = (const float*)d_in[22];
  const float* br_tg  = (const float*)d_in[23];
  const float* br_tbeta = (const float*)d_in[24];
  const float* mp_pw  = (const float*)d_in[25];
  const float* mp_pb  = (const float*)d_in[26];
  const float* mp_g1  = (const float*)d_in[27];
  const float* mp_b1  = (const float*)d_in[28];
  const float* mp_g2  = (const float*)d_in[29];
  const float* mp_b2  = (const float*)d_in[30];
  const float* p3w    = (const float*)d_in[31];
  const float* p3b    = (const float*)d_in[32];
  const float* p3g    = (const float*)d_in[33];
  const float* p3beta = (const float*)d_in[34];
  float* out = (float*)d_out;
  float* ws  = (float*)d_ws;

  // ws layout (float units, all 16B-aligned):
  float* xm_b    = ws;                                //   204,800 f32
  float* pooled  = ws + 204800;                       //     8,192 f32
  float* se_b    = ws + 212992;                       //     8,192 f32
  short* xbfT    = (short*)(ws + 221184);             // 26,214,400 bf16
  short* affbf   = (short*)(ws + 13328384);           // 25,165,824 bf16 [n][s][o][32u][32v]
  short* x3p     = (short*)(ws + 25911296);           // 25,165,824 bf16 (32-n chunk)
  short* ybn     = (short*)(ws + 38494208);           // 26,214,400 bf16
  short* c3wbf   = (short*)(ws + 51601408);           //    36,864 bf16
  short* w2g     = (short*)(ws + 51619840);           //     6,144 bf16 (end ~206.5MB)
  short* p_b     = (short*)(ws + 13328384);           // 19,660,800 bf16 [h][n][t][v][ic] (overlays affbf)

  k_cvt<<<dim3(6401),        dim3(256), 0, stream>>>(x, c3w, br_tw, xbfT, c3wbf, w2g);
  k_xm <<<dim3(N_ * C_),     dim3(256), 0, stream>>>(x, xm_b);
  k_aff<<<dim3(4, 3, N_),    dim3(256), 0, stream>>>(xm_b, PA, alpha, c1w, c1b, c2w, c2b,
                                                     c4w, c4b, affbf);
  for (int ch = 0; ch < 4; ++ch) {
    k_gemm1<<<dim3(50, 32), dim3(256), 0, stream>>>(xbfT, c3wbf, c3b, x3p, ch * 32);
    k_gemm2<<<dim3(16, 32), dim3(256), 0, stream>>>(x3p, affbf, gbn_g, gbn_b, ybn, pooled, ch * 32);
  }
  k_se <<<dim3(N_),          dim3(64),  0, stream>>>(pooled, att1_w, att1_b, att2_w, att2_b, se_b);
  k_pw <<<dim3(13, N_),      dim3(256), 0, stream>>>(ybn, se_b, x, br_pw, br_pb, br_pg, br_pbeta,
                                                     mp_pw, mp_pb, mp_g1, mp_b1,
                                                     p3w, p3b, p3g, p3beta, p_b, out);
  k_tcm<<<dim3(2, 2, N_),    dim3(256), 0, stream>>>(p_b, w2g, x, br_tb, br_tg, br_tbeta, out);
  k_mp <<<dim3(13, N_),      dim3(256), 0, stream>>>(p_b, x, mp_g2, mp_b2, out);
}

// Round 5
// 653.943 us; speedup vs baseline: 2.0568x; 1.0265x over previous
//
#include <hip/hip_runtime.h>
#include <hip/hip_bf16.h>
#include <math.h>

#define N_  128
#define C_  64
#define T_  128
#define V_  25
#define S_  3
#define R_  8
#define O_  64
#define BC_ 16
#define TV_ 3200   // T*V

typedef __attribute__((ext_vector_type(8))) short bf16x8;
typedef __attribute__((ext_vector_type(4))) float f32x4;

__device__ inline short f2bf(float f) {            // RNE float->bf16 (finite inputs)
  union { float f; unsigned u; } c; c.f = f;
  unsigned r = (c.u + 0x7FFFu + ((c.u >> 16) & 1u)) >> 16;
  return (short)r;
}
__device__ inline float bf2f(short s) {
  union { float f; unsigned u; } c; c.u = ((unsigned)(unsigned short)s) << 16;
  return c.f;
}

// ---------------- K0: x f32 [n][c][pos] -> xbfT bf16 [n][pos][c]; c3w->bf16;
//   bid==6400: prep w2g (temporal weights) + wcbf/wcsh (fused pointwise weights) ----
__global__ __launch_bounds__(256) void k_cvt(const float* __restrict__ x,
                                             const float* __restrict__ c3w,
                                             const float* __restrict__ br_tw,
                                             const float* __restrict__ br_pw,
                                             const float* __restrict__ br_pb,
                                             const float* __restrict__ br_pg,
                                             const float* __restrict__ br_pbeta,
                                             const float* __restrict__ mp_pw,
                                             const float* __restrict__ mp_pb,
                                             const float* __restrict__ mp_g1,
                                             const float* __restrict__ mp_b1,
                                             const float* __restrict__ p3w,
                                             const float* __restrict__ p3b,
                                             const float* __restrict__ p3g,
                                             const float* __restrict__ p3beta,
                                             short* __restrict__ xbfT,
                                             short* __restrict__ c3wbf,
                                             short* __restrict__ w2g,
                                             short* __restrict__ wcbf,
                                             float* __restrict__ wcsh) {
  int bid = blockIdx.x;                 // 6400 = 128 n * 50 pg, +1 prep block
  int tid = threadIdx.x;
  float rs = 1.0f / sqrtf(1.0f + 1e-5f);
  if (bid < 6400) {
    int n = bid / 50, pg = bid % 50;
    int w = tid >> 6, l = tid & 63;     // lane = channel c
    int p0 = pg * 64 + w * 16;
    const float* xp = x + ((size_t)n * 64 + l) * TV_ + p0;
    short* ob = xbfT + ((size_t)n * TV_ + p0) * 64 + l;
    #pragma unroll
    for (int q = 0; q < 4; ++q) {
      float4 xv = *(const float4*)(xp + q * 4);
      ob[(q * 4 + 0) * 64] = f2bf(xv.x);
      ob[(q * 4 + 1) * 64] = f2bf(xv.y);
      ob[(q * 4 + 2) * 64] = f2bf(xv.z);
      ob[(q * 4 + 3) * 64] = f2bf(xv.w);
    }
    if (bid < 144) {                    // 144*256 = 36864 = 3*64*64 c3w elems
      int i = bid * 256 + tid;
      c3wbf[i] = f2bf(c3w[i]);
    }
  } else {
    // w2g: plane0 = bf(W), plane1 = bf(W - f32(bf(W))); kidx = ktap*16+ic, pad to 96
    for (int i = tid; i < 6144; i += 256) {
      int plane = i / 3072, rem = i % 3072;
      int h = rem / 1536, rem2 = rem % 1536;
      int bc = rem2 / 96, kidx = rem2 % 96;
      short outv = 0;
      if (kidx < 80) {
        int ktap = kidx >> 4, ic = kidx & 15;
        float wv = br_tw[((h * 16 + bc) * 16 + ic) * 5 + ktap];
        short wb = f2bf(wv);
        outv = (plane == 0) ? wb : f2bf(wv - bf2f(wb));
      }
      w2g[i] = outv;
    }
    // wcbf[plane][64 rows][64 c]: fused pointwise weights, BN scale folded in.
    for (int i = tid; i < 4096; i += 256) {
      int r = i / 64, c = i % 64;
      int br = r >> 4, bc = r & 15;
      float wv, g;
      if (br < 2)      { wv = br_pw[br * 1024 + bc * 64 + c]; g = br_pg[br * 16 + bc]; }
      else if (br == 2){ wv = mp_pw[bc * 64 + c];             g = mp_g1[bc]; }
      else             { wv = p3w[bc * 64 + c];               g = p3g[bc]; }
      float ws_ = wv * (g * rs);
      short hi = f2bf(ws_);
      wcbf[i] = hi;
      wcbf[4096 + i] = f2bf(ws_ - bf2f(hi));
    }
    if (tid < 64) {
      int r = tid;
      int br = r >> 4, bc = r & 15;
      float g, pb, beta;
      if (br < 2)      { g = br_pg[br * 16 + bc]; pb = br_pb[br * 16 + bc]; beta = br_pbeta[br * 16 + bc]; }
      else if (br == 2){ g = mp_g1[bc];           pb = mp_pb[bc];           beta = mp_b1[bc]; }
      else             { g = p3g[bc];             pb = p3b[bc];             beta = p3beta[bc]; }
      wcsh[r] = fmaf(pb, g * rs, beta);
    }
  }
}

// ---------------- K1: xm[n][c][v] = mean over t ----------------
__global__ __launch_bounds__(256) void k_xm(const float* __restrict__ x,
                                            float* __restrict__ xm) {
  int nc = blockIdx.x;
  const float* xp = x + (size_t)nc * TV_;
  __shared__ float part[250];
  int tid = threadIdx.x;
  if (tid < 250) {
    float s = 0.f;
    for (int k = 0; k < 13; ++k) {
      int idx = tid + 250 * k;
      if (idx < TV_) s += xp[idx];
    }
    part[tid] = s;
  }
  __syncthreads();
  if (tid < 25) {
    float s = 0.f;
    #pragma unroll
    for (int g = 0; g < 10; ++g) s += part[g * 25 + tid];
    xm[(size_t)nc * V_ + tid] = s * (1.0f / 128.0f);
  }
}

// ---------------- K2: affinity -> softmax -> bf16 [n][s][o][u32][v32] (zero-padded) --
__global__ __launch_bounds__(256) void k_aff(
    const float* __restrict__ xm, const float* __restrict__ PA,
    const float* __restrict__ alpha,
    const float* __restrict__ c1w, const float* __restrict__ c1b,
    const float* __restrict__ c2w, const float* __restrict__ c2b,
    const float* __restrict__ c4w, const float* __restrict__ c4b,
    short* __restrict__ affbf) {
  int oq = blockIdx.x, s = blockIdx.y, n = blockIdx.z;
  int tid = threadIdx.x;
  __shared__ float xml[1600];
  __shared__ float w1[512], w2[512], w4l[512];
  __shared__ float x1l[200], x2l[200];
  __shared__ float dift[625 * 9];
  __shared__ float asym[625];
  short* ab = affbf + (((size_t)n * S_ + s) * 64) * 1024;   // [o][u32][v32]
  {
    int4 zz; zz.x = 0; zz.y = 0; zz.z = 0; zz.w = 0;
    int4* z0 = (int4*)(ab + (size_t)(oq * 8) * 1024);
    int4* z1 = (int4*)(ab + (size_t)(oq * 8 + 32) * 1024);
    for (int i = tid; i < 1024; i += 256) { z0[i] = zz; z1[i] = zz; }
  }
  for (int i = tid; i < 1600; i += 256) xml[i] = xm[(size_t)n * 1600 + i];
  for (int i = tid; i < 512; i += 256) {
    w1[i] = c1w[s * 512 + i];
    w2[i] = c2w[s * 512 + i];
    w4l[i] = c4w[s * 512 + i];
  }
  for (int i = tid; i < 625; i += 256) {
    int u = i / 25, v = i % 25;
    asym[i] = PA[s * 625 + u * 25 + v] + PA[s * 625 + v * 25 + u];
  }
  __syncthreads();
  if (tid < 200) {
    int r = tid / 25, v = tid % 25;
    float a1 = c1b[s * R_ + r], a2 = c2b[s * R_ + r];
    #pragma unroll
    for (int c = 0; c < 64; ++c) {
      float xv = xml[c * 25 + v];
      a1 = fmaf(w1[r * 64 + c], xv, a1);
      a2 = fmaf(w2[r * 64 + c], xv, a2);
    }
    x1l[tid] = a1; x2l[tid] = a2;
  }
  __syncthreads();
  for (int i = tid; i < 5000; i += 256) {
    int r = i / 625, rem = i % 625, u = rem / 25, v = rem % 25;
    dift[(u * 25 + v) * 9 + r] = tanhf(x1l[r * 25 + u] - x2l[r * 25 + v]);
  }
  __syncthreads();
  float al = alpha[s];
  if (tid < 200) {
    int ol = tid / 25, v = tid % 25;
    int oA = oq * 8 + ol, oB = oA + 32;
    float avA[25], avB[25];
    float bA = c4b[s * O_ + oA], bB = c4b[s * O_ + oB];
    #pragma unroll
    for (int u = 0; u < 25; ++u) { avA[u] = bA; avB[u] = bB; }
    #pragma unroll
    for (int u = 0; u < 25; ++u) {
      const float* dp = &dift[(u * 25 + v) * 9];
      #pragma unroll
      for (int r = 0; r < 8; ++r) {
        float d = dp[r];
        avA[u] = fmaf(w4l[oA * 8 + r], d, avA[u]);
        avB[u] = fmaf(w4l[oB * 8 + r], d, avB[u]);
      }
    }
    float mA = -1e30f, mB = -1e30f;
    #pragma unroll
    for (int u = 0; u < 25; ++u) {
      float as_ = asym[u * 25 + v];
      avA[u] = fmaf(avA[u], al, as_);
      avB[u] = fmaf(avB[u], al, as_);
      mA = fmaxf(mA, avA[u]); mB = fmaxf(mB, avB[u]);
    }
    float sA = 0.f, sB = 0.f;
    #pragma unroll
    for (int u = 0; u < 25; ++u) {
      avA[u] = expf(avA[u] - mA); sA += avA[u];
      avB[u] = expf(avB[u] - mB); sB += avB[u];
    }
    float iA = 1.0f / sA, iB = 1.0f / sB;
    #pragma unroll
    for (int u = 0; u < 25; ++u) {
      ab[(size_t)oA * 1024 + u * 32 + v] = f2bf(avA[u] * iA);
      ab[(size_t)oB * 1024 + u * 32 + v] = f2bf(avB[u] * iB);
    }
  }
}

// ---------------- K3: x3[nn][s][o][t][v32] = MFMA( c3w[s,o,c], x[n,c,t,v] ) + bias --
__global__ __launch_bounds__(256) void k_gemm1(
    const short* __restrict__ xbfT, const short* __restrict__ c3wbf,
    const float* __restrict__ c3b, short* __restrict__ x3p, int n0) {
  int pt = blockIdx.x;
  int nn = blockIdx.y;
  int n = n0 + nn;
  int tid = threadIdx.x, w = tid >> 6, l = tid & 63;
  int lr = l & 15, lg = l >> 4;
  const short* xb = xbfT + ((size_t)n * TV_ + pt * 64) * 64;
  bf16x8 B[4][2];
  #pragma unroll
  for (int sub = 0; sub < 4; ++sub) {
    const short* rp = xb + (sub * 16 + lr) * 64 + lg * 8;
    B[sub][0] = *(const bf16x8*)(rp);
    B[sub][1] = *(const bf16x8*)(rp + 32);
  }
  bf16x8 A[3][2];
  #pragma unroll
  for (int m = 0; m < 3; ++m) {
    const short* rp = c3wbf + (size_t)((w * 3 + m) * 16 + lr) * 64 + lg * 8;
    A[m][0] = *(const bf16x8*)(rp);
    A[m][1] = *(const bf16x8*)(rp + 32);
  }
  f32x4 acc[3][4];
  #pragma unroll
  for (int m = 0; m < 3; ++m)
    #pragma unroll
    for (int sub = 0; sub < 4; ++sub) acc[m][sub] = (f32x4)(0.f);
  #pragma unroll
  for (int m = 0; m < 3; ++m)
    #pragma unroll
    for (int sub = 0; sub < 4; ++sub) {
      acc[m][sub] = __builtin_amdgcn_mfma_f32_16x16x32_bf16(A[m][0], B[sub][0], acc[m][sub], 0, 0, 0);
      acc[m][sub] = __builtin_amdgcn_mfma_f32_16x16x32_bf16(A[m][1], B[sub][1], acc[m][sub], 0, 0, 0);
    }
  int tl[4], vl[4];
  #pragma unroll
  for (int sub = 0; sub < 4; ++sub) {
    int pos = pt * 64 + sub * 16 + lr;
    tl[sub] = pos / 25; vl[sub] = pos - tl[sub] * 25;
  }
  #pragma unroll
  for (int m = 0; m < 3; ++m) {
    int mt = w * 3 + m;
    #pragma unroll
    for (int j = 0; j < 4; ++j) {
      int r = mt * 16 + lg * 4 + j;          // 0..191 = s*64+o
      float bias = c3b[r];
      short* orow = x3p + (((size_t)nn * 192 + r) * 128) * 32;
      #pragma unroll
      for (int sub = 0; sub < 4; ++sub) {
        orow[tl[sub] * 32 + vl[sub]] = f2bf(acc[m][sub][j] + bias);
      }
    }
  }
}

// ---------------- K4: y = MFMA( x3[t][v32], aff[u32][v32]^T ) + BN; pooled sums ----
__global__ __launch_bounds__(256) void k_gemm2(
    const short* __restrict__ x3p, const short* __restrict__ affbf,
    const float* __restrict__ gbn_g, const float* __restrict__ gbn_b,
    short* __restrict__ ybn, float* __restrict__ pooled, int n0) {
  int og = blockIdx.x;
  int nn = blockIdx.y;
  int n = n0 + nn;
  int tid = threadIdx.x, w = tid >> 6, l = tid & 63;
  int lr = l & 15, lg = l >> 4;
  int o = og * 4 + w;
  f32x4 acc[8][2];
  #pragma unroll
  for (int mt = 0; mt < 8; ++mt) { acc[mt][0] = (f32x4)(0.f); acc[mt][1] = (f32x4)(0.f); }
  const short* xb = x3p + (((size_t)nn * 3) * 64 + o) * 4096;
  const short* ab = affbf + (((size_t)n * 3) * 64 + o) * 1024;
  #pragma unroll
  for (int s = 0; s < 3; ++s) {
    const short* abs_ = ab + (size_t)s * 64 * 1024;
    bf16x8 Bf[2];
    Bf[0] = *(const bf16x8*)(abs_ + (0 * 16 + lr) * 32 + lg * 8);
    Bf[1] = *(const bf16x8*)(abs_ + (1 * 16 + lr) * 32 + lg * 8);
    const short* xbs = xb + (size_t)s * 64 * 4096;
    #pragma unroll
    for (int mt = 0; mt < 8; ++mt) {
      bf16x8 Af = *(const bf16x8*)(xbs + (mt * 16 + lr) * 32 + lg * 8);
      acc[mt][0] = __builtin_amdgcn_mfma_f32_16x16x32_bf16(Af, Bf[0], acc[mt][0], 0, 0, 0);
      acc[mt][1] = __builtin_amdgcn_mfma_f32_16x16x32_bf16(Af, Bf[1], acc[mt][1], 0, 0, 0);
    }
  }
  float rs = 1.0f / sqrtf(1.0f + 1e-5f);
  float sc = gbn_g[o] * rs, bb = gbn_b[o];
  short* yb = ybn + ((size_t)n * 64 + o) * TV_;
  float lsum = 0.f;
  #pragma unroll
  for (int mt = 0; mt < 8; ++mt) {
    #pragma unroll
    for (int j = 0; j < 4; ++j) {
      int t = mt * 16 + lg * 4 + j;
      float v0 = fmaf(acc[mt][0][j], sc, bb);          // u = lr < 16
      yb[t * 25 + lr] = f2bf(v0); lsum += v0;
      if (lr < 9) {
        float v1 = fmaf(acc[mt][1][j], sc, bb);        // u = 16 + lr
        yb[t * 25 + 16 + lr] = f2bf(v1); lsum += v1;
      }
    }
  }
  #pragma unroll
  for (int off = 32; off > 0; off >>= 1) lsum += __shfl_down(lsum, off);
  if (l == 0) pooled[(size_t)n * 64 + o] = lsum;
}

// ---------------- K5: squeeze-excite gate ----------------
__global__ __launch_bounds__(64) void k_se(
    const float* __restrict__ pooled,
    const float* __restrict__ att1_w, const float* __restrict__ att1_b,
    const float* __restrict__ att2_w, const float* __restrict__ att2_b,
    float* __restrict__ se) {
  int n = blockIdx.x; int tid = threadIdx.x;
  __shared__ float pl[64]; __shared__ float hbuf[16];
  pl[tid] = pooled[(size_t)n * 64 + tid] * (1.0f / 3200.0f);
  __syncthreads();
  if (tid < 16) {
    float a = att1_b[tid];
    #pragma unroll
    for (int o = 0; o < 64; ++o) a = fmaf(att1_w[tid * 64 + o], pl[o], a);
    hbuf[tid] = fmaxf(a, 0.f);
  }
  __syncthreads();
  float a2 = att2_b[tid];
  #pragma unroll
  for (int k = 0; k < 16; ++k) a2 = fmaf(att2_w[tid * 16 + k], hbuf[k], a2);
  se[(size_t)n * 64 + tid] = 1.0f / (1.0f + expf(-a2));
}

// ---------------- K6: fused pointwise GEMM: y2 -> {3x pbuf branches, p3->out} ----
// block = (pt 0..24 of 128 pos, n). Phase 1: y2 = relu(ybn*se+x) -> LDS bf16 hi/lo
// planes, [pos][c] with 16B-chunk XOR swizzle. Phase 2: wave w = branch w, MFMA
// D[64 rows][128 pos] with 3 plane-products (f32-accurate), fused epilogue.
__global__ __launch_bounds__(256) void k_pwm(
    const short* __restrict__ ybn, const float* __restrict__ se,
    const float* __restrict__ x,
    const short* __restrict__ wcbf, const float* __restrict__ wcsh,
    short* __restrict__ pbuf, float* __restrict__ outp) {
  int pt = blockIdx.x; int n = blockIdx.y;
  int tid = threadIdx.x;
  __shared__ short yl[2][128 * 64];      // 32 KB
  {
    int posL = tid & 127, ch = tid >> 7;
    int pos0 = pt * 128;
    const float* sep = se + (size_t)n * 64;
    float y2r[32];
    #pragma unroll
    for (int i = 0; i < 32; ++i) {
      int c = ch * 32 + i;
      size_t a = ((size_t)n * 64 + c) * TV_ + pos0 + posL;
      float xv = x[a];
      float yv = bf2f(ybn[a]);
      y2r[i] = fmaxf(fmaf(yv, sep[c], xv), 0.f);
    }
    #pragma unroll
    for (int q = 0; q < 4; ++q) {
      bf16x8 hi, lo;
      #pragma unroll
      for (int j = 0; j < 8; ++j) {
        float v = y2r[q * 8 + j];
        short hb = f2bf(v);
        hi[j] = hb;
        lo[j] = f2bf(v - bf2f(hb));
      }
      int cc = ch * 4 + q;
      int ccs = cc ^ (posL & 7);
      *(bf16x8*)&yl[0][posL * 64 + ccs * 8] = hi;
      *(bf16x8*)&yl[1][posL * 64 + ccs * 8] = lo;
    }
  }
  __syncthreads();
  int w = tid >> 6, l = tid & 63;
  int lr = l & 15, lg = l >> 4;
  // A-frags: rows w*16+lr, K-chunk kk*32+lg*8; plane 0 and 1
  bf16x8 A0[2], A1[2];
  #pragma unroll
  for (int kk = 0; kk < 2; ++kk) {
    A0[kk] = *(const bf16x8*)(wcbf +        (w * 16 + lr) * 64 + kk * 32 + lg * 8);
    A1[kk] = *(const bf16x8*)(wcbf + 4096 + (w * 16 + lr) * 64 + kk * 32 + lg * 8);
  }
  float shf[4];
  #pragma unroll
  for (int j = 0; j < 4; ++j) shf[j] = wcsh[w * 16 + lg * 4 + j];
  #pragma unroll
  for (int nt = 0; nt < 8; ++nt) {
    int posL = nt * 16 + lr;
    f32x4 acc = (f32x4)(0.f);
    #pragma unroll
    for (int kk = 0; kk < 2; ++kk) {
      int ccs = (kk * 4 + lg) ^ (posL & 7);
      bf16x8 B0 = *(const bf16x8*)&yl[0][posL * 64 + ccs * 8];
      bf16x8 B1 = *(const bf16x8*)&yl[1][posL * 64 + ccs * 8];
      acc = __builtin_amdgcn_mfma_f32_16x16x32_bf16(A0[kk], B0, acc, 0, 0, 0);
      acc = __builtin_amdgcn_mfma_f32_16x16x32_bf16(A0[kk], B1, acc, 0, 0, 0);
      acc = __builtin_amdgcn_mfma_f32_16x16x32_bf16(A1[kk], B0, acc, 0, 0, 0);
    }
    int pos = pt * 128 + posL;
    if (w < 3) {                         // pbuf branches, post-BN relu, bf16
      short4 pk;
      pk.x = f2bf(fmaxf(acc[0] + shf[0], 0.f));
      pk.y = f2bf(fmaxf(acc[1] + shf[1], 0.f));
      pk.z = f2bf(fmaxf(acc[2] + shf[2], 0.f));
      pk.w = f2bf(fmaxf(acc[3] + shf[3], 0.f));
      *(short4*)&pbuf[(((size_t)w * N_ + n) * TV_ + pos) * 16 + lg * 4] = pk;
    } else {                             // p3 branch: + residual x, relu, f32 out
      #pragma unroll
      for (int j = 0; j < 4; ++j) {
        int ch8 = 48 + lg * 4 + j;
        size_t oa = ((size_t)n * 64 + ch8) * TV_ + pos;
        outp[oa] = fmaxf(acc[j] + shf[j] + x[oa], 0.f);
      }
    }
  }
}

// ---------------- K7: temporal conv via MFMA (im2col over LDS tile) --------------
__global__ __launch_bounds__(256) void k_tcm(
    const short* __restrict__ pbuf, const short* __restrict__ w2g,
    const float* __restrict__ x,
    const float* __restrict__ br_tb, const float* __restrict__ br_tg,
    const float* __restrict__ br_tbeta,
    float* __restrict__ outp) {
  int tt = blockIdx.x, h = blockIdx.y, n = blockIdx.z;
  int d = 1 + h;
  int tid = threadIdx.x, w = tid >> 6, l = tid & 63;
  int lr = l & 15, lg = l >> 4;
  __shared__ short ptile[72 * 25 * 16];   // 57,600 B: rows t0-4 .. t0+67 (zero halo)
  {
    const int4* src = (const int4*)(pbuf + ((size_t)(h * N_ + n) * TV_) * 16);
    int4* dst = (int4*)ptile;
    int4 zz; zz.x = 0; zz.y = 0; zz.z = 0; zz.w = 0;
    for (int u = tid; u < 3600; u += 256) {      // 72 rows x 50 int4/row
      int r = u / 50, q = u - r * 50;
      int t = tt * 64 - 4 + r;
      dst[u] = (t >= 0 && t < T_) ? src[t * 50 + q] : zz;
    }
  }
  bf16x8 Af0[3], Af1[3];
  #pragma unroll
  for (int ks = 0; ks < 3; ++ks) {
    Af0[ks] = *(const bf16x8*)(w2g + ((0 * 2 + h) * 16 + lr) * 96 + ks * 32 + lg * 8);
    Af1[ks] = *(const bf16x8*)(w2g + ((1 * 2 + h) * 16 + lr) * 96 + ks * 32 + lg * 8);
  }
  float rs = 1.0f / sqrtf(1.0f + 1e-5f);
  float scl[4], shf[4];
  #pragma unroll
  for (int j = 0; j < 4; ++j) {
    int bc = lg * 4 + j;
    float sc = br_tg[h * 16 + bc] * rs;
    scl[j] = sc;
    shf[j] = fmaf(br_tb[h * 16 + bc], sc, br_tbeta[h * 16 + bc]);
  }
  __syncthreads();
  for (int nt = w; nt < 100; nt += 4) {
    int posL = nt * 16 + lr;
    int tL = posL / 25, v = posL - tL * 25;
    f32x4 acc = (f32x4)(0.f);
    #pragma unroll
    for (int ks = 0; ks < 3; ++ks) {
      int ktap = 2 * ks + (lg >> 1);
      int ic0 = (lg & 1) * 8;
      int r = tL + 4 + (ktap - 2) * d;
      r = min(r, 71);
      bf16x8 Bf = *(const bf16x8*)(ptile + (r * 25 + v) * 16 + ic0);
      acc = __builtin_amdgcn_mfma_f32_16x16x32_bf16(Af0[ks], Bf, acc, 0, 0, 0);
      acc = __builtin_amdgcn_mfma_f32_16x16x32_bf16(Af1[ks], Bf, acc, 0, 0, 0);
    }
    int gpos = tt * 1600 + posL;
    #pragma unroll
    for (int j = 0; j < 4; ++j) {
      int ch = h * 16 + lg * 4 + j;
      size_t oa = ((size_t)n * 64 + ch) * TV_ + gpos;
      float xv = x[oa];
      outp[oa] = fmaxf(fmaf(acc[j], scl[j], shf[j]) + xv, 0.f);
    }
  }
}

// ---------------- K8: maxpool branch + BN + residual + relu ----------------
__global__ __launch_bounds__(256) void k_mp(
    const short* __restrict__ pbuf, const float* __restrict__ x,
    const float* __restrict__ mp_g2, const float* __restrict__ mp_b2,
    float* __restrict__ outp) {
  int tt = blockIdx.x, n = blockIdx.y;
  int t0 = tt * 10;
  int npos = min(10, T_ - t0) * 25;
  int tid = threadIdx.x;
  if (tid >= npos) return;
  int pos = t0 * 25 + tid;
  int t = pos / 25, v = pos - t * 25;
  const short* pb = pbuf + ((size_t)(2 * N_ + n) * TV_) * 16;
  int tm = max(t - 1, 0), tp = min(t + 1, T_ - 1);
  bf16x8 a0 = *(const bf16x8*)(pb + (tm * 25 + v) * 16);
  bf16x8 a1 = *(const bf16x8*)(pb + (tm * 25 + v) * 16 + 8);
  bf16x8 b0 = *(const bf16x8*)(pb + (t  * 25 + v) * 16);
  bf16x8 b1 = *(const bf16x8*)(pb + (t  * 25 + v) * 16 + 8);
  bf16x8 c0 = *(const bf16x8*)(pb + (tp * 25 + v) * 16);
  bf16x8 c1 = *(const bf16x8*)(pb + (tp * 25 + v) * 16 + 8);
  float rs = 1.0f / sqrtf(1.0f + 1e-5f);
  #pragma unroll
  for (int i = 0; i < 8; ++i) {
    float m0 = fmaxf(fmaxf(bf2f(a0[i]), bf2f(b0[i])), bf2f(c0[i]));
    float m1 = fmaxf(fmaxf(bf2f(a1[i]), bf2f(b1[i])), bf2f(c1[i]));
    size_t oa0 = ((size_t)n * 64 + 32 + i) * TV_ + pos;
    size_t oa1 = ((size_t)n * 64 + 40 + i) * TV_ + pos;
    float v0 = fmaf(m0, mp_g2[i] * rs, mp_b2[i]);
    float v1 = fmaf(m1, mp_g2[8 + i] * rs, mp_b2[8 + i]);
    outp[oa0] = fmaxf(v0 + x[oa0], 0.f);
    outp[oa1] = fmaxf(v1 + x[oa1], 0.f);
  }
}

extern "C" void kernel_launch(void* const* d_in, const int* in_sizes, int n_in,
                              void* d_out, int out_size, void* d_ws, size_t ws_size,
                              hipStream_t stream) {
  (void)in_sizes; (void)n_in; (void)out_size; (void)ws_size;
  const float* x      = (const float*)d_in[0];
  const float* PA     = (const float*)d_in[1];
  const float* alpha  = (const float*)d_in[2];
  const float* c1w    = (const float*)d_in[3];
  const float* c1b    = (const float*)d_in[4];
  const float* c2w    = (const float*)d_in[5];
  const float* c2b    = (const float*)d_in[6];
  const float* c3w    = (const float*)d_in[7];
  const float* c3b    = (const float*)d_in[8];
  const float* c4w    = (const float*)d_in[9];
  const float* c4b    = (const float*)d_in[10];
  const float* gbn_g  = (const float*)d_in[11];
  const float* gbn_b  = (const float*)d_in[12];
  const float* att1_w = (const float*)d_in[13];
  const float* att1_b = (const float*)d_in[14];
  const float* att2_w = (const float*)d_in[15];
  const float* att2_b = (const float*)d_in[16];
  const float* br_pw  = (const float*)d_in[17];
  const float* br_pb  = (const float*)d_in[18];
  const float* br_pg  = (const float*)d_in[19];
  const float* br_pbeta = (const float*)d_in[20];
  const float* br_tw  = (const float*)d_in[21];
  const float* br_tb  = (const float*)d_in[22];
  const float* br_tg  = (const float*)d_in[23];
  const float* br_tbeta = (const float*)d_in[24];
  const float* mp_pw  = (const float*)d_in[25];
  const float* mp_pb  = (const float*)d_in[26];
  const float* mp_g1  = (const float*)d_in[27];
  const float* mp_b1  = (const float*)d_in[28];
  const float* mp_g2  = (const float*)d_in[29];
  const float* mp_b2  = (const float*)d_in[30];
  const float* p3w    = (const float*)d_in[31];
  const float* p3b    = (const float*)d_in[32];
  const float* p3g    = (const float*)d_in[33];
  const float* p3beta = (const float*)d_in[34];
  float* out = (float*)d_out;
  float* ws  = (float*)d_ws;

  // ws layout (float units, all 16B-aligned):
  float* xm_b    = ws;                                //   204,800 f32
  float* pooled  = ws + 204800;                       //     8,192 f32
  float* se_b    = ws + 212992;                       //     8,192 f32
  short* xbfT    = (short*)(ws + 221184);             // 26,214,400 bf16
  short* affbf   = (short*)(ws + 13328384);           // 25,165,824 bf16 [n][s][o][32u][32v]
  short* x3p     = (short*)(ws + 25911296);           // 25,165,824 bf16 (32-n chunk)
  short* ybn     = (short*)(ws + 38494208);           // 26,214,400 bf16
  short* c3wbf   = (short*)(ws + 51601408);           //    36,864 bf16
  short* w2g     = (short*)(ws + 51619840);           //     6,144 bf16
  short* wcbf    = (short*)(ws + 51622912);           //     8,192 bf16 (2 planes x 64 x 64)
  float* wcsh    = ws + 51627008;                     //        64 f32 (end ~206.5MB)
  short* p_b     = (short*)(ws + 13328384);           // 19,660,800 bf16 [h][n][t][v][ic] (overlays affbf)

  k_cvt<<<dim3(6401),        dim3(256), 0, stream>>>(x, c3w, br_tw,
                                                     br_pw, br_pb, br_pg, br_pbeta,
                                                     mp_pw, mp_pb, mp_g1, mp_b1,
                                                     p3w, p3b, p3g, p3beta,
                                                     xbfT, c3wbf, w2g, wcbf, wcsh);
  k_xm <<<dim3(N_ * C_),     dim3(256), 0, stream>>>(x, xm_b);
  k_aff<<<dim3(4, 3, N_),    dim3(256), 0, stream>>>(xm_b, PA, alpha, c1w, c1b, c2w, c2b,
                                                     c4w, c4b, affbf);
  for (int ch = 0; ch < 4; ++ch) {
    k_gemm1<<<dim3(50, 32), dim3(256), 0, stream>>>(xbfT, c3wbf, c3b, x3p, ch * 32);
    k_gemm2<<<dim3(16, 32), dim3(256), 0, stream>>>(x3p, affbf, gbn_g, gbn_b, ybn, pooled, ch * 32);
  }
  k_se <<<dim3(N_),          dim3(64),  0, stream>>>(pooled, att1_w, att1_b, att2_w, att2_b, se_b);
  k_pwm<<<dim3(25, N_),      dim3(256), 0, stream>>>(ybn, se_b, x, wcbf, wcsh, p_b, out);
  k_tcm<<<dim3(2, 2, N_),    dim3(256), 0, stream>>>(p_b, w2g, x, br_tb, br_tg, br_tbeta, out);
  k_mp <<<dim3(13, N_),      dim3(256), 0, stream>>>(p_b, x, mp_g2, mp_b2, out);
}